// Round 10
// baseline (325.289 us; speedup 1.0000x reference)
//
#include <hip/hip_runtime.h>
#include <cstddef>

#define NEGV (-1e12f)

// Sizes (fixed): B=64, N=256, H=512, HEADS=8, DK=64, NBINS=3

typedef __attribute__((ext_vector_type(4))) float f32x4;
typedef __attribute__((ext_vector_type(8))) __bf16 bf16x8;

__device__ __forceinline__ unsigned short f2bf(float f) {
  union { float f; unsigned u; } v; v.f = f;
  unsigned r = v.u + 0x7FFFu + ((v.u >> 16) & 1u);   // round-nearest-even
  return (unsigned short)(r >> 16);
}

#define GLDS16(gp, lp)                                                      \
  __builtin_amdgcn_global_load_lds(                                         \
      (const __attribute__((address_space(1))) void*)(gp),                  \
      (__attribute__((address_space(3))) void*)(lp), 16, 0, 0)

// ---------------------------------------------------------------------------
// Mega-prep (unchanged)
__global__ __launch_bounds__(256) void msa_prep(
    const float* __restrict__ x, const float* __restrict__ Wq,
    const float* __restrict__ Wk, const float* __restrict__ Wv,
    const float* __restrict__ Ws2, const float* __restrict__ Ws1,
    const float* __restrict__ Wa, const float* __restrict__ bq,
    const float* __restrict__ bk, const float* __restrict__ bv,
    const float* __restrict__ ba, const float* __restrict__ bs1,
    const float* __restrict__ dist, const float* __restrict__ dist_bar,
    const float* __restrict__ maskg,
    unsigned short* __restrict__ xb, unsigned short* __restrict__ Wqkvb,
    unsigned short* __restrict__ Ws2b, unsigned short* __restrict__ Wcatb,
    float* __restrict__ bcomb, float* __restrict__ bqkv,
    unsigned long long* __restrict__ bits) {
  __shared__ float As[16][68];
  __shared__ float Bs[16][68];
  const int blk = blockIdx.x;
  const int tid = threadIdx.x;
  if (blk < 8192) {                                   // xb
    int i = blk * 256 + tid;
    float4 v = ((const float4*)x)[i];
    ushort4 o; o.x = f2bf(v.x); o.y = f2bf(v.y); o.z = f2bf(v.z); o.w = f2bf(v.w);
    ((ushort4*)xb)[i] = o;
    return;
  }
  if (blk < 8960) {                                   // weight f2b
    int sel = (blk - 8192) >> 8;                      // 0..2
    int i = ((blk - 8192) & 255) * 256 + tid;
    const float* src = (sel == 0) ? Wq : (sel == 1) ? Wk : Wv;
    unsigned short* dst = Wqkvb + (size_t)sel * 262144;
    float4 v = ((const float4*)src)[i];
    ushort4 o; o.x = f2bf(v.x); o.y = f2bf(v.y); o.z = f2bf(v.z); o.w = f2bf(v.w);
    ((ushort4*)dst)[i] = o;
    return;
  }
  if (blk < 9216) {                                   // Ws2b
    int i = (blk - 8960) * 256 + tid;
    float4 v = ((const float4*)Ws2)[i];
    ushort4 o; o.x = f2bf(v.x); o.y = f2bf(v.y); o.z = f2bf(v.z); o.w = f2bf(v.w);
    ((ushort4*)Ws2b)[i] = o;
    return;
  }
  if (blk < 9408) {                                   // Wcat tile
    const int t = blk - 9216;
    const int i = t >> 6;
    const int ob = ((t >> 3) & 7) * 64, cb = (t & 7) * 64;
    const int tx = tid & 15, ty = tid >> 4;
    float acc[4][4] = {};
    for (int kt = 0; kt < 512; kt += 16) {
      __syncthreads();
      {
        int o = tid & 63, e4 = (tid >> 6) * 4;
        float4 a4 = *(const float4*)&Ws1[(size_t)(ob + o) * 1536 + i * 512 + kt + e4];
        As[e4 + 0][o] = a4.x; As[e4 + 1][o] = a4.y;
        As[e4 + 2][o] = a4.z; As[e4 + 3][o] = a4.w;
      }
      {
        int e = tid & 15, c4 = (tid >> 4) * 4;
        float4 b4 = *(const float4*)&Wa[((size_t)i << 18) + (size_t)(kt + e) * 512 + cb + c4];
        *(float4*)&Bs[e][c4] = b4;
      }
      __syncthreads();
#pragma unroll
      for (int k = 0; k < 16; ++k) {
        float a[4], bb[4];
        *(float4*)a = *(const float4*)&As[k][ty * 4];
        *(float4*)bb = *(const float4*)&Bs[k][tx * 4];
#pragma unroll
        for (int r = 0; r < 4; ++r)
#pragma unroll
          for (int c = 0; c < 4; ++c) acc[r][c] += a[r] * bb[c];
      }
    }
#pragma unroll
    for (int r = 0; r < 4; ++r)
#pragma unroll
      for (int c = 0; c < 4; ++c)
        Wcatb[(size_t)(ob + ty * 4 + r) * 1536 + i * 512 + cb + tx * 4 + c] =
            f2bf(acc[r][c]);
    return;
  }
  if (blk < 9410) {                                   // bcomb
    int o = (blk - 9408) * 256 + tid;
    float acc = bs1[o];
    for (int cidx = 0; cidx < 1536; ++cidx)
      acc += Ws1[(size_t)o * 1536 + cidx] * ba[cidx];
    bcomb[o] = acc;
    return;
  }
  if (blk < 9411) {                                   // bqkv concat
    for (int i = tid; i < 1536; i += 256)
      bqkv[i] = (i < 512) ? bq[i] : (i < 1024) ? bk[i - 512] : bv[i - 1024];
    return;
  }
  {                                                   // keep-bits
    const int gw = (blk - 9411) * 4 + (tid >> 6);
    const int lane = tid & 63;
    const int b = gw >> 8, row = gw & 255;
    const float cut0 = dist_bar[b * 3 + 0];
    const float cut1 = dist_bar[b * 3 + 1];
    const float cut2 = dist_bar[b * 3 + 2];
    const float* mrow = maskg + (size_t)b * 65536 + (size_t)row * 256;
    const int rj = (row == 0) ? 1 : row;
    const float* drow = dist + (size_t)b * 65025 + (size_t)(rj - 1) * 255;
    unsigned long long* out = bits + (size_t)gw * 12;
#pragma unroll
    for (int cc = 0; cc < 4; ++cc) {
      const int col = cc * 64 + lane;
      const int cj = (col == 0) ? 1 : col;
      float dv = drow[cj - 1];
      bool sup = (row == 0) || (col == 0);
      bool mk = (mrow[col] != 0.f);
      if (sup) dv = -1e30f;
      unsigned long long b0 = __ballot(mk && (dv < cut0));
      unsigned long long b1 = __ballot(mk && (dv < cut1));
      unsigned long long b2 = __ballot(mk && (dv < cut2));
      if (lane == 0) { out[cc] = b0; out[4 + cc] = b1; out[8 + cc] = b2; }
    }
  }
}

// ---------------------------------------------------------------------------
// bf16 MFMA NT GEMM, 2-phase double-buffered, parameterized BK (unchanged)
template <int ACT, int RES, int OBF, int BK>
__global__ __launch_bounds__(256) void msa_gemm_mfma(
    const unsigned short* __restrict__ A, int lda,
    const unsigned short* __restrict__ W, int ldw,
    const float* __restrict__ bias, const float* __restrict__ resid,
    void* __restrict__ Cout, int ldc, int Kdim) {
  constexpr int KSUB = BK / 32;
  constexpr int RPC = BK / 8;
  constexpr int CPT = (128 * RPC) / 256;
  __shared__ __align__(16) unsigned short Asm_[2][128 * BK];
  __shared__ __align__(16) unsigned short Bsm_[2][128 * BK];
  const int tid = threadIdx.x;
  const int lane = tid & 63, wv = tid >> 6;
  const int m0 = blockIdx.x * 128, n0 = blockIdx.y * 128;
  const int wr = wv >> 1, wc = wv & 1;
  const int fr = lane & 15, fq = lane >> 4;
  f32x4 acc[4][4] = {};
  const unsigned short* Ag[CPT];
  const unsigned short* Wg[CPT];
#pragma unroll
  for (int i = 0; i < CPT; ++i) {
    int c = tid + i * 256;
    int row = c / RPC, j = c % RPC;
    Ag[i] = A + (size_t)(m0 + row) * lda + j * 8;
    Wg[i] = W + (size_t)(n0 + row) * ldw + j * 8;
  }
#pragma unroll
  for (int i = 0; i < CPT; ++i) {
    GLDS16(Ag[i], &Asm_[0][(tid + i * 256) * 8]);
    GLDS16(Wg[i], &Bsm_[0][(tid + i * 256) * 8]);
  }
  __syncthreads();
  int cur = 0;
  for (int kt = 0; kt < Kdim; kt += BK) {
    if (kt + BK < Kdim) {
      const int nx = cur ^ 1, k2 = kt + BK;
#pragma unroll
      for (int i = 0; i < CPT; ++i) {
        GLDS16(Ag[i] + k2, &Asm_[nx][(tid + i * 256) * 8]);
        GLDS16(Wg[i] + k2, &Bsm_[nx][(tid + i * 256) * 8]);
      }
    }
#pragma unroll
    for (int ks = 0; ks < KSUB; ++ks) {
      bf16x8 af[4], bfr[4];
#pragma unroll
      for (int mf = 0; mf < 4; ++mf)
        af[mf] = *(const bf16x8*)&Asm_[cur][(wr * 64 + mf * 16 + fr) * BK + ks * 32 + fq * 8];
#pragma unroll
      for (int nf = 0; nf < 4; ++nf)
        bfr[nf] = *(const bf16x8*)&Bsm_[cur][(wc * 64 + nf * 16 + fr) * BK + ks * 32 + fq * 8];
#pragma unroll
      for (int mf = 0; mf < 4; ++mf)
#pragma unroll
        for (int nf = 0; nf < 4; ++nf)
          acc[mf][nf] = __builtin_amdgcn_mfma_f32_16x16x32_bf16(
              af[mf], bfr[nf], acc[mf][nf], 0, 0, 0);
    }
    __syncthreads();
    cur ^= 1;
  }
#pragma unroll
  for (int mf = 0; mf < 4; ++mf) {
#pragma unroll
    for (int nf = 0; nf < 4; ++nf) {
      const int n = n0 + wc * 64 + nf * 16 + fr;
      const float bval = bias[n];
#pragma unroll
      for (int r = 0; r < 4; ++r) {
        const int m = m0 + wr * 64 + mf * 16 + fq * 4 + r;
        float val = acc[mf][nf][r] + bval;
        if (ACT == 1) val = val / (1.f + __expf(-val));
        if (RES == 1) val += resid[(size_t)m * ldc + n];
        if (OBF == 1)
          ((unsigned short*)Cout)[(size_t)m * ldc + n] = f2bf(val);
        else
          ((float*)Cout)[(size_t)m * ldc + n] = val;
      }
    }
  }
}

// ---------------------------------------------------------------------------
// Fused attention with SWAPPED QK^T: accs = mfma(K_frag, Q_frag) = S^T frags.
// Lane (l15, fq) holds S[k=16nt+4fq+r][q=r0+l15] -> row q lane-local per l15
// across fq groups: softmax reduce = local chain + shfl_xor(16,32).
// P stores: float4 (4 consecutive k). Pl: [16][256] bf16/wave, b64 writes,
// XOR-swizzled ((l15&1)<<6)|((l15&2)<<4) on both write and read.
__global__ __launch_bounds__(512) void msa_fused(
    const unsigned short* __restrict__ qkvb,
    const unsigned long long* __restrict__ bits,
    float* __restrict__ attn_out, unsigned short* __restrict__ mob) {
  const int blk = blockIdx.x;
  const int b = (blk & 7) * 8 + (blk >> 6);   // bijective on [0,512)
  const int h = (blk >> 3) & 7;
  __shared__ __align__(16) unsigned short Kl[256][72];     // 36864 B
  __shared__ __align__(16) unsigned short Vt[64][264];     // 33792 B
  __shared__ __align__(16) unsigned short Pl[8][16][256];  // 65536 B
  const int tid = threadIdx.x;
  const int wv = tid >> 6, lane = tid & 63;
  const int l15 = lane & 15, fq = lane >> 4;
  // --- stage K ---
  {
    const unsigned short* kgp = qkvb + (size_t)(b * 256) * 1536 + 512 + h * 64;
#pragma unroll
    for (int i = 0; i < 4; ++i) {
      int s = tid + i * 512;
      int row = s >> 3, c8 = (s & 7) << 3;
      *(uint4*)&Kl[row][c8] = *(const uint4*)&kgp[(size_t)row * 1536 + c8];
    }
  }
  // --- stage V transposed ---
  {
    int rv = tid & 255, half = tid >> 8;
    const unsigned short* vgp =
        qkvb + (size_t)(b * 256 + rv) * 1536 + 1024 + h * 64 + half * 32;
#pragma unroll
    for (int j4 = 0; j4 < 4; ++j4) {
      unsigned short tmp[8];
      *(uint4*)tmp = *(const uint4*)&vgp[j4 * 8];
#pragma unroll
      for (int j = 0; j < 8; ++j) Vt[half * 32 + j4 * 8 + j][rv] = tmp[j];
    }
  }
  __syncthreads();
  char* plbase = (char*)&Pl[wv][0][0];
  const int swz = ((l15 & 1) << 6) | ((l15 & 2) << 4);
#pragma unroll
  for (int mf = 0; mf < 2; ++mf) {
    const int r0 = wv * 32 + mf * 16;
    const int q = r0 + l15;
    const unsigned short* qgp =
        qkvb + (size_t)(b * 256 + q) * 1536 + h * 64 + fq * 8;
    bf16x8 aq0 = *(const bf16x8*)qgp;
    bf16x8 aq1 = *(const bf16x8*)(qgp + 32);
    f32x4 accs[16];
#pragma unroll
    for (int nt = 0; nt < 16; ++nt) {
      bf16x8 bk0 = *(const bf16x8*)&Kl[nt * 16 + l15][fq * 8];
      bf16x8 bk1 = *(const bf16x8*)&Kl[nt * 16 + l15][32 + fq * 8];
      f32x4 a = {};
      a = __builtin_amdgcn_mfma_f32_16x16x32_bf16(bk0, aq0, a, 0, 0, 0);  // swapped
      a = __builtin_amdgcn_mfma_f32_16x16x32_bf16(bk1, aq1, a, 0, 0, 0);
      accs[nt] = a;
    }
    const unsigned long long* brow = bits + (size_t)(b * 256 + q) * 12;
#pragma unroll
    for (int bin = 0; bin < 3; ++bin) {
      const unsigned long long w0 = brow[bin * 4 + 0];
      const unsigned long long w1 = brow[bin * 4 + 1];
      const unsigned long long w2 = brow[bin * 4 + 2];
      const unsigned long long w3 = brow[bin * 4 + 3];
      f32x4 p[16];
      float m = -3e38f;
#pragma unroll
      for (int nt = 0; nt < 16; ++nt) {
        unsigned long long w = (nt < 4) ? w0 : (nt < 8) ? w1 : (nt < 12) ? w2 : w3;
#pragma unroll
        for (int r = 0; r < 4; ++r) {
          unsigned keep = (unsigned)(w >> (16 * (nt & 3) + 4 * fq + r)) & 1u;
          float sv = accs[nt][r] * 0.125f;
          float v = keep ? sv : NEGV;
          p[nt][r] = v;
          m = fmaxf(m, v);
        }
      }
      m = fmaxf(m, __shfl_xor(m, 16));
      m = fmaxf(m, __shfl_xor(m, 32));
      float sum = 0.f;
#pragma unroll
      for (int nt = 0; nt < 16; ++nt)
#pragma unroll
        for (int r = 0; r < 4; ++r) {
          p[nt][r] = __expf(p[nt][r] - m);
          sum += p[nt][r];
        }
      sum += __shfl_xor(sum, 16);
      sum += __shfl_xor(sum, 32);
      const float inv = 1.f / sum;
      float* prow = attn_out + ((size_t)((bin * 64 + b) * 8 + h)) * 65536 +
                    (size_t)q * 256;
#pragma unroll
      for (int nt = 0; nt < 16; ++nt) {
        float v0 = p[nt][0] * inv, v1 = p[nt][1] * inv;
        float v2 = p[nt][2] * inv, v3 = p[nt][3] * inv;
        *(float4*)(prow + nt * 16 + fq * 4) = make_float4(v0, v1, v2, v3);
        unsigned short u[4];
        u[0] = f2bf(v0); u[1] = f2bf(v1); u[2] = f2bf(v2); u[3] = f2bf(v3);
        int wb = (l15 << 9) | (nt << 5) | (fq << 3);
        *(uint2*)(plbase + (wb ^ swz)) = *(const uint2*)u;
      }
      asm volatile("s_waitcnt lgkmcnt(0)" ::: "memory");
      __builtin_amdgcn_sched_barrier(0);
      f32x4 acco[4] = {};
#pragma unroll
      for (int c = 0; c < 8; ++c) {
        int rb = (l15 << 9) | (c << 6) | (fq << 4);
        bf16x8 pa = *(const bf16x8*)(plbase + (rb ^ swz));
#pragma unroll
        for (int nf = 0; nf < 4; ++nf) {
          bf16x8 bv = *(const bf16x8*)&Vt[nf * 16 + l15][c * 32 + fq * 8];
          acco[nf] = __builtin_amdgcn_mfma_f32_16x16x32_bf16(pa, bv, acco[nf], 0, 0, 0);
        }
      }
#pragma unroll
      for (int nf = 0; nf < 4; ++nf)
#pragma unroll
        for (int r = 0; r < 4; ++r)
          mob[((size_t)(b * 256 + r0 + fq * 4 + r) * 3 + bin) * 512 +
              h * 64 + nf * 16 + l15] = f2bf(acco[nf][r]);
      // Pl reused next bin: lgkmcnt(0) below PV reads already drained by use;
      // writes of next bin ordered after these reads by per-wave LDS ordering.
      asm volatile("s_waitcnt lgkmcnt(0)" ::: "memory");
      __builtin_amdgcn_sched_barrier(0);
    }
  }
}

// ---------------------------------------------------------------------------
// Fused mlp2 + residual + LayerNorm (unchanged from round 9)
__global__ __launch_bounds__(256) void msa_mlp2ln(
    const unsigned short* __restrict__ h1b, const unsigned short* __restrict__ Ws2b,
    const float* __restrict__ bs2, const float* __restrict__ x,
    const float* __restrict__ gamma, const float* __restrict__ beta,
    float* __restrict__ outp) {
  __shared__ __align__(16) unsigned short Al[32 * 32];
  __shared__ __align__(16) unsigned short Bl[512 * 32];
  __shared__ float red[2][2][32];
  const int tid = threadIdx.x;
  const int lane = tid & 63, wv = tid >> 6;
  const int wr = wv >> 1, wc = wv & 1;
  const int l15 = lane & 15, fq = lane >> 4;
  const int m0 = blockIdx.x * 32;
  f32x4 acc[16] = {};
  for (int kt = 0; kt < 512; kt += 32) {
    if (tid < 128) {
      int row = tid >> 2, c8 = (tid & 3) * 8;
      GLDS16(h1b + (size_t)(m0 + row) * 512 + kt + c8, &Al[tid * 8]);
    }
#pragma unroll
    for (int i = 0; i < 8; ++i) {
      int c = tid + i * 256;
      int row = c >> 2, c8 = (c & 3) * 8;
      GLDS16(Ws2b + (size_t)row * 512 + kt + c8, &Bl[c * 8]);
    }
    __syncthreads();
    bf16x8 af = *(const bf16x8*)&Al[(wr * 16 + l15) * 32 + fq * 8];
#pragma unroll
    for (int nt = 0; nt < 16; ++nt) {
      bf16x8 bfr = *(const bf16x8*)&Bl[(wc * 256 + nt * 16 + l15) * 32 + fq * 8];
      acc[nt] = __builtin_amdgcn_mfma_f32_16x16x32_bf16(af, bfr, acc[nt], 0, 0, 0);
    }
    __syncthreads();
  }
  float vals[16][4];
#pragma unroll
  for (int nt = 0; nt < 16; ++nt) {
    const int n = wc * 256 + nt * 16 + l15;
    const float bval = bs2[n];
#pragma unroll
    for (int r = 0; r < 4; ++r) {
      const int m = m0 + wr * 16 + fq * 4 + r;
      vals[nt][r] = acc[nt][r] + bval + x[(size_t)m * 512 + n];
    }
  }
  const int ridx = wr * 16 + fq * 4;
#pragma unroll
  for (int r = 0; r < 4; ++r) {
    float s = 0.f;
#pragma unroll
    for (int nt = 0; nt < 16; ++nt) s += vals[nt][r];
    s += __shfl_xor(s, 1); s += __shfl_xor(s, 2);
    s += __shfl_xor(s, 4); s += __shfl_xor(s, 8);
    if (l15 == 0) red[0][wc][ridx + r] = s;
  }
  __syncthreads();
  float mu[4];
#pragma unroll
  for (int r = 0; r < 4; ++r)
    mu[r] = (red[0][0][ridx + r] + red[0][1][ridx + r]) * (1.f / 512.f);
#pragma unroll
  for (int r = 0; r < 4; ++r) {
    float s = 0.f;
#pragma unroll
    for (int nt = 0; nt < 16; ++nt) {
      float d = vals[nt][r] - mu[r];
      s += d * d;
    }
    s += __shfl_xor(s, 1); s += __shfl_xor(s, 2);
    s += __shfl_xor(s, 4); s += __shfl_xor(s, 8);
    if (l15 == 0) red[1][wc][ridx + r] = s;
  }
  __syncthreads();
  float iv[4];
#pragma unroll
  for (int r = 0; r < 4; ++r) {
    float var = (red[1][0][ridx + r] + red[1][1][ridx + r]) * (1.f / 512.f);
    iv[r] = 1.f / sqrtf(var + 1e-6f);
  }
#pragma unroll
  for (int nt = 0; nt < 16; ++nt) {
    const int n = wc * 256 + nt * 16 + l15;
    const float g = gamma[n], be = beta[n];
#pragma unroll
    for (int r = 0; r < 4; ++r) {
      const int m = m0 + wr * 16 + fq * 4 + r;
      outp[(size_t)m * 512 + n] = (vals[nt][r] - mu[r]) * iv[r] * g + be;
    }
  }
}

// ---------------------------------------------------------------------------
extern "C" void kernel_launch(void* const* d_in, const int* in_sizes, int n_in,
                              void* d_out, int out_size, void* d_ws, size_t ws_size,
                              hipStream_t stream) {
  (void)in_sizes; (void)n_in; (void)out_size; (void)ws_size;
  const float* x        = (const float*)d_in[0];
  const float* dist     = (const float*)d_in[1];
  const float* dist_bar = (const float*)d_in[2];
  const float* mask     = (const float*)d_in[3];
  const float* Wq  = (const float*)d_in[4];  const float* bq  = (const float*)d_in[5];
  const float* Wk  = (const float*)d_in[6];  const float* bk  = (const float*)d_in[7];
  const float* Wv  = (const float*)d_in[8];  const float* bv  = (const float*)d_in[9];
  const float* Wa  = (const float*)d_in[10]; const float* ba  = (const float*)d_in[11];
  const float* Ws1 = (const float*)d_in[12]; const float* bs1 = (const float*)d_in[13];
  const float* Ws2 = (const float*)d_in[14]; const float* bs2 = (const float*)d_in[15];
  const float* gamma = (const float*)d_in[16]; const float* beta = (const float*)d_in[17];

  char* w8 = (char*)d_ws;
  const size_t SZ = 8388608;                         // 16384*512
  unsigned short* qkvb = (unsigned short*)(w8 + 0);            // 50.3 MB [16384][1536]
  unsigned short* mob  = (unsigned short*)(w8 + 50331648);     // 50.3 MB [16384][1536]
  unsigned short* xb   = (unsigned short*)(w8 + 100663296);    // 16.8 MB
  unsigned short* Wqkvb= (unsigned short*)(w8 + 117440512);    // 1.6 MB [1536][512]
  unsigned short* Ws2b = (unsigned short*)(w8 + 119013376);    // 0.5 MB
  unsigned short* Wcatb= (unsigned short*)(w8 + 119537664);    // 1.6 MB [512][1536]
  float* bcomb = (float*)(w8 + 121110528);                     // 2 KB
  float* bqkv  = (float*)(w8 + 121112576);                     // 6 KB
  unsigned long long* bits = (unsigned long long*)(w8 + 121118720);  // 1.6 MB
  unsigned short* h1b = qkvb;                        // qkvb dead after msa_fused
  float* outp = (float*)d_out;
  float* attn = outp + SZ;                           // [3,B,8,256,256] fp32

  msa_prep<<<13507, 256, 0, stream>>>(x, Wq, Wk, Wv, Ws2, Ws1, Wa, bq, bk, bv,
                                      ba, bs1, dist, dist_bar, mask,
                                      xb, Wqkvb, Ws2b, Wcatb, bcomb, bqkv, bits);

  // qkv = x @ [Wq;Wk;Wv]^T + bqkv
  msa_gemm_mfma<0, 0, 1, 32><<<dim3(128, 12), 256, 0, stream>>>(
      xb, 512, Wqkvb, 512, bqkv, nullptr, qkvb, 1536, 512);

  msa_fused<<<512, 512, 0, stream>>>(qkvb, bits, attn, mob);

  // h1b = silu(mob @ Wcatb^T + bcomb)
  msa_gemm_mfma<1, 0, 1, 64><<<dim3(128, 4), 256, 0, stream>>>(
      mob, 1536, Wcatb, 1536, bcomb, nullptr, h1b, 512, 1536);

  // out = LN(h1b @ Ws2b^T + bs2 + x) * gamma + beta
  msa_mlp2ln<<<512, 256, 0, stream>>>(h1b, Ws2b, bs2, x, gamma, beta, outp);
}

// Round 12
// 307.078 us; speedup vs baseline: 1.0593x; 1.0593x over previous
//
#include <hip/hip_runtime.h>
#include <cstddef>

#define NEGV (-1e12f)

// Sizes (fixed): B=64, N=256, H=512, HEADS=8, DK=64, NBINS=3

typedef __attribute__((ext_vector_type(4))) float f32x4;
typedef __attribute__((ext_vector_type(8))) __bf16 bf16x8;

__device__ __forceinline__ unsigned short f2bf(float f) {
  union { float f; unsigned u; } v; v.f = f;
  unsigned r = v.u + 0x7FFFu + ((v.u >> 16) & 1u);   // round-nearest-even
  return (unsigned short)(r >> 16);
}

#define GLDS16(gp, lp)                                                      \
  __builtin_amdgcn_global_load_lds(                                         \
      (const __attribute__((address_space(1))) void*)(gp),                  \
      (__attribute__((address_space(3))) void*)(lp), 16, 0, 0)

// ---------------------------------------------------------------------------
// Mega-prep. Block-range ladder:
//  [0,8192)       xb = bf16(x)
//  [8192,8960)    Wqkvb = bf16(Wq|Wk|Wv)
//  [8960,9216)    Ws2b = bf16(Ws2)
//  [9216,9600)    Wcat tiles (384 blocks: 3 bins x 16x8 of 32x64)
//  [9600,9728)    bcomb (wave-parallel, 4 o's per block)
//  [9728]         bqkv concat
//  [9729,13825)   keep-bits
__global__ __launch_bounds__(256) void msa_prep(
    const float* __restrict__ x, const float* __restrict__ Wq,
    const float* __restrict__ Wk, const float* __restrict__ Wv,
    const float* __restrict__ Ws2, const float* __restrict__ Ws1,
    const float* __restrict__ Wa, const float* __restrict__ bq,
    const float* __restrict__ bk, const float* __restrict__ bv,
    const float* __restrict__ ba, const float* __restrict__ bs1,
    const float* __restrict__ dist, const float* __restrict__ dist_bar,
    const float* __restrict__ maskg,
    unsigned short* __restrict__ xb, unsigned short* __restrict__ Wqkvb,
    unsigned short* __restrict__ Ws2b, unsigned short* __restrict__ Wcatb,
    float* __restrict__ bcomb, float* __restrict__ bqkv,
    unsigned long long* __restrict__ bits) {
  __shared__ float As[16][36];
  __shared__ float Bs[16][68];
  const int blk = blockIdx.x;
  const int tid = threadIdx.x;
  if (blk < 8192) {                                   // xb
    int i = blk * 256 + tid;
    float4 v = ((const float4*)x)[i];
    ushort4 o; o.x = f2bf(v.x); o.y = f2bf(v.y); o.z = f2bf(v.z); o.w = f2bf(v.w);
    ((ushort4*)xb)[i] = o;
    return;
  }
  if (blk < 8960) {                                   // weight f2b
    int sel = (blk - 8192) >> 8;                      // 0..2
    int i = ((blk - 8192) & 255) * 256 + tid;
    const float* src = (sel == 0) ? Wq : (sel == 1) ? Wk : Wv;
    unsigned short* dst = Wqkvb + (size_t)sel * 262144;
    float4 v = ((const float4*)src)[i];
    ushort4 o; o.x = f2bf(v.x); o.y = f2bf(v.y); o.z = f2bf(v.z); o.w = f2bf(v.w);
    ((ushort4*)dst)[i] = o;
    return;
  }
  if (blk < 9216) {                                   // Ws2b
    int i = (blk - 8960) * 256 + tid;
    float4 v = ((const float4*)Ws2)[i];
    ushort4 o; o.x = f2bf(v.x); o.y = f2bf(v.y); o.z = f2bf(v.z); o.w = f2bf(v.w);
    ((ushort4*)Ws2b)[i] = o;
    return;
  }
  if (blk < 9600) {                                   // Wcat 32x64 tile
    const int t = blk - 9216;                         // [0,384)
    const int i = t >> 7;                             // bin
    const int rem = t & 127;
    const int ob = (rem >> 3) * 32, cb = (rem & 7) * 64;
    const int tx = tid & 15, ty = tid >> 4;
    float acc[2][4] = {};
    for (int kt = 0; kt < 512; kt += 16) {
      __syncthreads();
      if (tid < 128) {
        int o = tid >> 2, e4 = (tid & 3) * 4;
        float4 a4 = *(const float4*)&Ws1[(size_t)(ob + o) * 1536 + i * 512 + kt + e4];
        As[e4 + 0][o] = a4.x; As[e4 + 1][o] = a4.y;
        As[e4 + 2][o] = a4.z; As[e4 + 3][o] = a4.w;
      }
      {
        int e = tid & 15, c4 = (tid >> 4) * 4;
        float4 b4 = *(const float4*)&Wa[((size_t)i << 18) + (size_t)(kt + e) * 512 + cb + c4];
        *(float4*)&Bs[e][c4] = b4;
      }
      __syncthreads();
#pragma unroll
      for (int k = 0; k < 16; ++k) {
        float a0 = As[k][ty * 2], a1 = As[k][ty * 2 + 1];
        float bb[4];
        *(float4*)bb = *(const float4*)&Bs[k][tx * 4];
#pragma unroll
        for (int c = 0; c < 4; ++c) {
          acc[0][c] += a0 * bb[c];
          acc[1][c] += a1 * bb[c];
        }
      }
    }
#pragma unroll
    for (int rr = 0; rr < 2; ++rr)
#pragma unroll
      for (int c = 0; c < 4; ++c)
        Wcatb[(size_t)(ob + ty * 2 + rr) * 1536 + i * 512 + cb + tx * 4 + c] =
            f2bf(acc[rr][c]);
    return;
  }
  if (blk < 9728) {                                   // bcomb: wave per o
    const int o = (blk - 9600) * 4 + (tid >> 6);
    const int lane = tid & 63;
    const float* row = Ws1 + (size_t)o * 1536;
    float s = 0.f;
#pragma unroll
    for (int c0 = 0; c0 < 1536; c0 += 256) {
      s += row[c0 + lane] * ba[c0 + lane];
      s += row[c0 + 64 + lane] * ba[c0 + 64 + lane];
      s += row[c0 + 128 + lane] * ba[c0 + 128 + lane];
      s += row[c0 + 192 + lane] * ba[c0 + 192 + lane];
    }
#pragma unroll
    for (int off = 32; off > 0; off >>= 1) s += __shfl_xor(s, off);
    if (lane == 0) bcomb[o] = bs1[o] + s;
    return;
  }
  if (blk < 9729) {                                   // bqkv concat
    for (int i = tid; i < 1536; i += 256)
      bqkv[i] = (i < 512) ? bq[i] : (i < 1024) ? bk[i - 512] : bv[i - 1024];
    return;
  }
  {                                                   // keep-bits
    const int gw = (blk - 9729) * 4 + (tid >> 6);
    const int lane = tid & 63;
    const int b = gw >> 8, row = gw & 255;
    const float cut0 = dist_bar[b * 3 + 0];
    const float cut1 = dist_bar[b * 3 + 1];
    const float cut2 = dist_bar[b * 3 + 2];
    const float* mrow = maskg + (size_t)b * 65536 + (size_t)row * 256;
    const int rj = (row == 0) ? 1 : row;
    const float* drow = dist + (size_t)b * 65025 + (size_t)(rj - 1) * 255;
    unsigned long long* out = bits + (size_t)gw * 12;
#pragma unroll
    for (int cc = 0; cc < 4; ++cc) {
      const int col = cc * 64 + lane;
      const int cj = (col == 0) ? 1 : col;
      float dv = drow[cj - 1];
      bool sup = (row == 0) || (col == 0);
      bool mk = (mrow[col] != 0.f);
      if (sup) dv = -1e30f;
      unsigned long long b0 = __ballot(mk && (dv < cut0));
      unsigned long long b1 = __ballot(mk && (dv < cut1));
      unsigned long long b2 = __ballot(mk && (dv < cut2));
      if (lane == 0) { out[cc] = b0; out[4 + cc] = b1; out[8 + cc] = b2; }
    }
  }
}

// ---------------------------------------------------------------------------
// bf16 MFMA NT GEMM, 2-phase double-buffered; SQ=1 scales n<512 by 0.125.
template <int ACT, int RES, int OBF, int BK, int SQ>
__global__ __launch_bounds__(256) void msa_gemm_mfma(
    const unsigned short* __restrict__ A, int lda,
    const unsigned short* __restrict__ W, int ldw,
    const float* __restrict__ bias, const float* __restrict__ resid,
    void* __restrict__ Cout, int ldc, int Kdim) {
  constexpr int KSUB = BK / 32;
  constexpr int RPC = BK / 8;
  constexpr int CPT = (128 * RPC) / 256;
  __shared__ __align__(16) unsigned short Asm_[2][128 * BK];
  __shared__ __align__(16) unsigned short Bsm_[2][128 * BK];
  const int tid = threadIdx.x;
  const int lane = tid & 63, wv = tid >> 6;
  const int m0 = blockIdx.x * 128, n0 = blockIdx.y * 128;
  const int wr = wv >> 1, wc = wv & 1;
  const int fr = lane & 15, fq = lane >> 4;
  f32x4 acc[4][4] = {};
  const unsigned short* Ag[CPT];
  const unsigned short* Wg[CPT];
#pragma unroll
  for (int i = 0; i < CPT; ++i) {
    int c = tid + i * 256;
    int row = c / RPC, j = c % RPC;
    Ag[i] = A + (size_t)(m0 + row) * lda + j * 8;
    Wg[i] = W + (size_t)(n0 + row) * ldw + j * 8;
  }
#pragma unroll
  for (int i = 0; i < CPT; ++i) {
    GLDS16(Ag[i], &Asm_[0][(tid + i * 256) * 8]);
    GLDS16(Wg[i], &Bsm_[0][(tid + i * 256) * 8]);
  }
  __syncthreads();
  int cur = 0;
  for (int kt = 0; kt < Kdim; kt += BK) {
    if (kt + BK < Kdim) {
      const int nx = cur ^ 1, k2 = kt + BK;
#pragma unroll
      for (int i = 0; i < CPT; ++i) {
        GLDS16(Ag[i] + k2, &Asm_[nx][(tid + i * 256) * 8]);
        GLDS16(Wg[i] + k2, &Bsm_[nx][(tid + i * 256) * 8]);
      }
    }
#pragma unroll
    for (int ks = 0; ks < KSUB; ++ks) {
      bf16x8 af[4], bfr[4];
#pragma unroll
      for (int mf = 0; mf < 4; ++mf)
        af[mf] = *(const bf16x8*)&Asm_[cur][(wr * 64 + mf * 16 + fr) * BK + ks * 32 + fq * 8];
#pragma unroll
      for (int nf = 0; nf < 4; ++nf)
        bfr[nf] = *(const bf16x8*)&Bsm_[cur][(wc * 64 + nf * 16 + fr) * BK + ks * 32 + fq * 8];
#pragma unroll
      for (int mf = 0; mf < 4; ++mf)
#pragma unroll
        for (int nf = 0; nf < 4; ++nf)
          acc[mf][nf] = __builtin_amdgcn_mfma_f32_16x16x32_bf16(
              af[mf], bfr[nf], acc[mf][nf], 0, 0, 0);
    }
    __syncthreads();
    cur ^= 1;
  }
#pragma unroll
  for (int mf = 0; mf < 4; ++mf) {
#pragma unroll
    for (int nf = 0; nf < 4; ++nf) {
      const int n = n0 + wc * 64 + nf * 16 + fr;
      const float bval = bias[n];
#pragma unroll
      for (int r = 0; r < 4; ++r) {
        const int m = m0 + wr * 64 + mf * 16 + fq * 4 + r;
        float val = acc[mf][nf][r] + bval;
        if (SQ == 1 && n < 512) val *= 0.125f;        // fold 1/sqrt(dk) into q
        if (ACT == 1) val = val / (1.f + __expf(-val));
        if (RES == 1) val += resid[(size_t)m * ldc + n];
        if (OBF == 1)
          ((unsigned short*)Cout)[(size_t)m * ldc + n] = f2bf(val);
        else
          ((float*)Cout)[(size_t)m * ldc + n] = val;
      }
    }
  }
}

// ---------------------------------------------------------------------------
// Fused attention (swapped QK^T; q pre-scaled by 0.125; NT stores for attn)
__global__ __launch_bounds__(512) void msa_fused(
    const unsigned short* __restrict__ qkvb,
    const unsigned long long* __restrict__ bits,
    float* __restrict__ attn_out, unsigned short* __restrict__ mob) {
  const int blk = blockIdx.x;
  const int b = (blk & 7) * 8 + (blk >> 6);   // bijective on [0,512)
  const int h = (blk >> 3) & 7;
  __shared__ __align__(16) unsigned short Kl[256][72];     // 36864 B
  __shared__ __align__(16) unsigned short Vt[64][264];     // 33792 B
  __shared__ __align__(16) unsigned short Pl[8][16][256];  // 65536 B
  const int tid = threadIdx.x;
  const int wv = tid >> 6, lane = tid & 63;
  const int l15 = lane & 15, fq = lane >> 4;
  // --- stage K ---
  {
    const unsigned short* kgp = qkvb + (size_t)(b * 256) * 1536 + 512 + h * 64;
#pragma unroll
    for (int i = 0; i < 4; ++i) {
      int s = tid + i * 512;
      int row = s >> 3, c8 = (s & 7) << 3;
      *(uint4*)&Kl[row][c8] = *(const uint4*)&kgp[(size_t)row * 1536 + c8];
    }
  }
  // --- stage V transposed ---
  {
    int rv = tid & 255, half = tid >> 8;
    const unsigned short* vgp =
        qkvb + (size_t)(b * 256 + rv) * 1536 + 1024 + h * 64 + half * 32;
#pragma unroll
    for (int j4 = 0; j4 < 4; ++j4) {
      unsigned short tmp[8];
      *(uint4*)tmp = *(const uint4*)&vgp[j4 * 8];
#pragma unroll
      for (int j = 0; j < 8; ++j) Vt[half * 32 + j4 * 8 + j][rv] = tmp[j];
    }
  }
  __syncthreads();
  char* plbase = (char*)&Pl[wv][0][0];
  const int swz = ((l15 & 1) << 6) | ((l15 & 2) << 4);
#pragma unroll
  for (int mf = 0; mf < 2; ++mf) {
    const int r0 = wv * 32 + mf * 16;
    const int q = r0 + l15;
    const unsigned short* qgp =
        qkvb + (size_t)(b * 256 + q) * 1536 + h * 64 + fq * 8;
    bf16x8 aq0 = *(const bf16x8*)qgp;
    bf16x8 aq1 = *(const bf16x8*)(qgp + 32);
    f32x4 accs[16];
#pragma unroll
    for (int nt = 0; nt < 16; ++nt) {
      bf16x8 bk0 = *(const bf16x8*)&Kl[nt * 16 + l15][fq * 8];
      bf16x8 bk1 = *(const bf16x8*)&Kl[nt * 16 + l15][32 + fq * 8];
      f32x4 a = {};
      a = __builtin_amdgcn_mfma_f32_16x16x32_bf16(bk0, aq0, a, 0, 0, 0);  // swapped
      a = __builtin_amdgcn_mfma_f32_16x16x32_bf16(bk1, aq1, a, 0, 0, 0);
      accs[nt] = a;
    }
    const unsigned long long* brow = bits + (size_t)(b * 256 + q) * 12;
#pragma unroll
    for (int bin = 0; bin < 3; ++bin) {
      const unsigned long long w0 = brow[bin * 4 + 0];
      const unsigned long long w1 = brow[bin * 4 + 1];
      const unsigned long long w2 = brow[bin * 4 + 2];
      const unsigned long long w3 = brow[bin * 4 + 3];
      f32x4 p[16];
      float m = -3e38f;
#pragma unroll
      for (int nt = 0; nt < 16; ++nt) {
        unsigned long long w = (nt < 4) ? w0 : (nt < 8) ? w1 : (nt < 12) ? w2 : w3;
#pragma unroll
        for (int r = 0; r < 4; ++r) {
          unsigned keep = (unsigned)(w >> (16 * (nt & 3) + 4 * fq + r)) & 1u;
          float sv = accs[nt][r];
          float v = keep ? sv : NEGV;
          p[nt][r] = v;
          m = fmaxf(m, v);
        }
      }
      m = fmaxf(m, __shfl_xor(m, 16));
      m = fmaxf(m, __shfl_xor(m, 32));
      float sum = 0.f;
#pragma unroll
      for (int nt = 0; nt < 16; ++nt)
#pragma unroll
        for (int r = 0; r < 4; ++r) {
          p[nt][r] = __expf(p[nt][r] - m);
          sum += p[nt][r];
        }
      sum += __shfl_xor(sum, 16);
      sum += __shfl_xor(sum, 32);
      const float inv = 1.f / sum;
      float* prow = attn_out + ((size_t)((bin * 64 + b) * 8 + h)) * 65536 +
                    (size_t)q * 256;
#pragma unroll
      for (int nt = 0; nt < 16; ++nt) {
        float v0 = p[nt][0] * inv, v1 = p[nt][1] * inv;
        float v2 = p[nt][2] * inv, v3 = p[nt][3] * inv;
        f32x4 st = {v0, v1, v2, v3};
        __builtin_nontemporal_store(st, (f32x4*)(prow + nt * 16 + fq * 4));
        unsigned short u[4];
        u[0] = f2bf(v0); u[1] = f2bf(v1); u[2] = f2bf(v2); u[3] = f2bf(v3);
        int wb = (l15 << 9) | (nt << 5) | (fq << 3);
        *(uint2*)(plbase + (wb ^ swz)) = *(const uint2*)u;
      }
      asm volatile("s_waitcnt lgkmcnt(0)" ::: "memory");
      __builtin_amdgcn_sched_barrier(0);
      f32x4 acco[4] = {};
#pragma unroll
      for (int c = 0; c < 8; ++c) {
        int rb = (l15 << 9) | (c << 6) | (fq << 4);
        bf16x8 pa = *(const bf16x8*)(plbase + (rb ^ swz));
#pragma unroll
        for (int nf = 0; nf < 4; ++nf) {
          bf16x8 bv = *(const bf16x8*)&Vt[nf * 16 + l15][c * 32 + fq * 8];
          acco[nf] = __builtin_amdgcn_mfma_f32_16x16x32_bf16(pa, bv, acco[nf], 0, 0, 0);
        }
      }
#pragma unroll
      for (int nf = 0; nf < 4; ++nf)
#pragma unroll
        for (int r = 0; r < 4; ++r)
          mob[((size_t)(b * 256 + r0 + fq * 4 + r) * 3 + bin) * 512 +
              h * 64 + nf * 16 + l15] = f2bf(acco[nf][r]);
      asm volatile("s_waitcnt lgkmcnt(0)" ::: "memory");
      __builtin_amdgcn_sched_barrier(0);
    }
  }
}

// ---------------------------------------------------------------------------
// Fused mlp2 + residual + LayerNorm (unchanged)
__global__ __launch_bounds__(256) void msa_mlp2ln(
    const unsigned short* __restrict__ h1b, const unsigned short* __restrict__ Ws2b,
    const float* __restrict__ bs2, const float* __restrict__ x,
    const float* __restrict__ gamma, const float* __restrict__ beta,
    float* __restrict__ outp) {
  __shared__ __align__(16) unsigned short Al[32 * 32];
  __shared__ __align__(16) unsigned short Bl[512 * 32];
  __shared__ float red[2][2][32];
  const int tid = threadIdx.x;
  const int lane = tid & 63, wv = tid >> 6;
  const int wr = wv >> 1, wc = wv & 1;
  const int l15 = lane & 15, fq = lane >> 4;
  const int m0 = blockIdx.x * 32;
  f32x4 acc[16] = {};
  for (int kt = 0; kt < 512; kt += 32) {
    if (tid < 128) {
      int row = tid >> 2, c8 = (tid & 3) * 8;
      GLDS16(h1b + (size_t)(m0 + row) * 512 + kt + c8, &Al[tid * 8]);
    }
#pragma unroll
    for (int i = 0; i < 8; ++i) {
      int c = tid + i * 256;
      int row = c >> 2, c8 = (c & 3) * 8;
      GLDS16(Ws2b + (size_t)row * 512 + kt + c8, &Bl[c * 8]);
    }
    __syncthreads();
    bf16x8 af = *(const bf16x8*)&Al[(wr * 16 + l15) * 32 + fq * 8];
#pragma unroll
    for (int nt = 0; nt < 16; ++nt) {
      bf16x8 bfr = *(const bf16x8*)&Bl[(wc * 256 + nt * 16 + l15) * 32 + fq * 8];
      acc[nt] = __builtin_amdgcn_mfma_f32_16x16x32_bf16(af, bfr, acc[nt], 0, 0, 0);
    }
    __syncthreads();
  }
  float vals[16][4];
#pragma unroll
  for (int nt = 0; nt < 16; ++nt) {
    const int n = wc * 256 + nt * 16 + l15;
    const float bval = bs2[n];
#pragma unroll
    for (int r = 0; r < 4; ++r) {
      const int m = m0 + wr * 16 + fq * 4 + r;
      vals[nt][r] = acc[nt][r] + bval + x[(size_t)m * 512 + n];
    }
  }
  const int ridx = wr * 16 + fq * 4;
#pragma unroll
  for (int r = 0; r < 4; ++r) {
    float s = 0.f;
#pragma unroll
    for (int nt = 0; nt < 16; ++nt) s += vals[nt][r];
    s += __shfl_xor(s, 1); s += __shfl_xor(s, 2);
    s += __shfl_xor(s, 4); s += __shfl_xor(s, 8);
    if (l15 == 0) red[0][wc][ridx + r] = s;
  }
  __syncthreads();
  float mu[4];
#pragma unroll
  for (int r = 0; r < 4; ++r)
    mu[r] = (red[0][0][ridx + r] + red[0][1][ridx + r]) * (1.f / 512.f);
#pragma unroll
  for (int r = 0; r < 4; ++r) {
    float s = 0.f;
#pragma unroll
    for (int nt = 0; nt < 16; ++nt) {
      float d = vals[nt][r] - mu[r];
      s += d * d;
    }
    s += __shfl_xor(s, 1); s += __shfl_xor(s, 2);
    s += __shfl_xor(s, 4); s += __shfl_xor(s, 8);
    if (l15 == 0) red[1][wc][ridx + r] = s;
  }
  __syncthreads();
  float iv[4];
#pragma unroll
  for (int r = 0; r < 4; ++r) {
    float var = (red[1][0][ridx + r] + red[1][1][ridx + r]) * (1.f / 512.f);
    iv[r] = 1.f / sqrtf(var + 1e-6f);
  }
#pragma unroll
  for (int nt = 0; nt < 16; ++nt) {
    const int n = wc * 256 + nt * 16 + l15;
    const float g = gamma[n], be = beta[n];
#pragma unroll
    for (int r = 0; r < 4; ++r) {
      const int m = m0 + wr * 16 + fq * 4 + r;
      outp[(size_t)m * 512 + n] = (vals[nt][r] - mu[r]) * iv[r] * g + be;
    }
  }
}

// ---------------------------------------------------------------------------
extern "C" void kernel_launch(void* const* d_in, const int* in_sizes, int n_in,
                              void* d_out, int out_size, void* d_ws, size_t ws_size,
                              hipStream_t stream) {
  (void)in_sizes; (void)n_in; (void)out_size; (void)ws_size;
  const float* x        = (const float*)d_in[0];
  const float* dist     = (const float*)d_in[1];
  const float* dist_bar = (const float*)d_in[2];
  const float* mask     = (const float*)d_in[3];
  const float* Wq  = (const float*)d_in[4];  const float* bq  = (const float*)d_in[5];
  const float* Wk  = (const float*)d_in[6];  const float* bk  = (const float*)d_in[7];
  const float* Wv  = (const float*)d_in[8];  const float* bv  = (const float*)d_in[9];
  const float* Wa  = (const float*)d_in[10]; const float* ba  = (const float*)d_in[11];
  const float* Ws1 = (const float*)d_in[12]; const float* bs1 = (const float*)d_in[13];
  const float* Ws2 = (const float*)d_in[14]; const float* bs2 = (const float*)d_in[15];
  const float* gamma = (const float*)d_in[16]; const float* beta = (const float*)d_in[17];

  char* w8 = (char*)d_ws;
  const size_t SZ = 8388608;                         // 16384*512
  unsigned short* qkvb = (unsigned short*)(w8 + 0);            // 50.3 MB [16384][1536]
  unsigned short* mob  = (unsigned short*)(w8 + 50331648);     // 50.3 MB [16384][1536]
  unsigned short* xb   = (unsigned short*)(w8 + 100663296);    // 16.8 MB
  unsigned short* Wqkvb= (unsigned short*)(w8 + 117440512);    // 1.6 MB [1536][512]
  unsigned short* Ws2b = (unsigned short*)(w8 + 119013376);    // 0.5 MB
  unsigned short* Wcatb= (unsigned short*)(w8 + 119537664);    // 1.6 MB [512][1536]
  float* bcomb = (float*)(w8 + 121110528);                     // 2 KB
  float* bqkv  = (float*)(w8 + 121112576);                     // 6 KB
  unsigned long long* bits = (unsigned long long*)(w8 + 121118720);  // 1.6 MB
  unsigned short* h1b = qkvb;                        // qkvb dead after msa_fused
  float* outp = (float*)d_out;
  float* attn = outp + SZ;                           // [3,B,8,256,256] fp32

  msa_prep<<<13825, 256, 0, stream>>>(x, Wq, Wk, Wv, Ws2, Ws1, Wa, bq, bk, bv,
                                      ba, bs1, dist, dist_bar, mask,
                                      xb, Wqkvb, Ws2b, Wcatb, bcomb, bqkv, bits);

  // qkv = x @ [Wq;Wk;Wv]^T + bqkv  (q columns pre-scaled by 0.125)
  msa_gemm_mfma<0, 0, 1, 32, 1><<<dim3(128, 12), 256, 0, stream>>>(
      xb, 512, Wqkvb, 512, bqkv, nullptr, qkvb, 1536, 512);

  msa_fused<<<512, 512, 0, stream>>>(qkvb, bits, attn, mob);

  // h1b = silu(mob @ Wcatb^T + bcomb)
  msa_gemm_mfma<1, 0, 1, 64, 0><<<dim3(128, 4), 256, 0, stream>>>(
      mob, 1536, Wcatb, 1536, bcomb, nullptr, h1b, 512, 1536);

  // out = LN(h1b @ Ws2b^T + bs2 + x) * gamma + beta
  msa_mlp2ln<<<512, 256, 0, stream>>>(h1b, Ws2b, bs2, x, gamma, beta, outp);
}

// Round 13
// 306.925 us; speedup vs baseline: 1.0598x; 1.0005x over previous
//
#include <hip/hip_runtime.h>
#include <cstddef>

#define NEGV (-1e12f)

// Sizes (fixed): B=64, N=256, H=512, HEADS=8, DK=64, NBINS=3

typedef __attribute__((ext_vector_type(4))) float f32x4;
typedef __attribute__((ext_vector_type(8))) __bf16 bf16x8;

__device__ __forceinline__ unsigned short f2bf(float f) {
  union { float f; unsigned u; } v; v.f = f;
  unsigned r = v.u + 0x7FFFu + ((v.u >> 16) & 1u);   // round-nearest-even
  return (unsigned short)(r >> 16);
}
__device__ __forceinline__ float bf2f(unsigned short u) {
  union { unsigned u; float f; } v; v.u = (unsigned)u << 16; return v.f;
}

#define GLDS16(gp, lp)                                                      \
  __builtin_amdgcn_global_load_lds(                                         \
      (const __attribute__((address_space(1))) void*)(gp),                  \
      (__attribute__((address_space(3))) void*)(lp), 16, 0, 0)

// ---------------------------------------------------------------------------
// Mega-prep (unchanged from round 12)
__global__ __launch_bounds__(256) void msa_prep(
    const float* __restrict__ x, const float* __restrict__ Wq,
    const float* __restrict__ Wk, const float* __restrict__ Wv,
    const float* __restrict__ Ws2, const float* __restrict__ Ws1,
    const float* __restrict__ Wa, const float* __restrict__ bq,
    const float* __restrict__ bk, const float* __restrict__ bv,
    const float* __restrict__ ba, const float* __restrict__ bs1,
    const float* __restrict__ dist, const float* __restrict__ dist_bar,
    const float* __restrict__ maskg,
    unsigned short* __restrict__ xb, unsigned short* __restrict__ Wqkvb,
    unsigned short* __restrict__ Ws2b, unsigned short* __restrict__ Wcatb,
    float* __restrict__ bcomb, float* __restrict__ bqkv,
    unsigned long long* __restrict__ bits) {
  __shared__ float As[16][36];
  __shared__ float Bs[16][68];
  const int blk = blockIdx.x;
  const int tid = threadIdx.x;
  if (blk < 8192) {                                   // xb
    int i = blk * 256 + tid;
    float4 v = ((const float4*)x)[i];
    ushort4 o; o.x = f2bf(v.x); o.y = f2bf(v.y); o.z = f2bf(v.z); o.w = f2bf(v.w);
    ((ushort4*)xb)[i] = o;
    return;
  }
  if (blk < 8960) {                                   // weight f2b
    int sel = (blk - 8192) >> 8;                      // 0..2
    int i = ((blk - 8192) & 255) * 256 + tid;
    const float* src = (sel == 0) ? Wq : (sel == 1) ? Wk : Wv;
    unsigned short* dst = Wqkvb + (size_t)sel * 262144;
    float4 v = ((const float4*)src)[i];
    ushort4 o; o.x = f2bf(v.x); o.y = f2bf(v.y); o.z = f2bf(v.z); o.w = f2bf(v.w);
    ((ushort4*)dst)[i] = o;
    return;
  }
  if (blk < 9216) {                                   // Ws2b
    int i = (blk - 8960) * 256 + tid;
    float4 v = ((const float4*)Ws2)[i];
    ushort4 o; o.x = f2bf(v.x); o.y = f2bf(v.y); o.z = f2bf(v.z); o.w = f2bf(v.w);
    ((ushort4*)Ws2b)[i] = o;
    return;
  }
  if (blk < 9600) {                                   // Wcat 32x64 tile
    const int t = blk - 9216;                         // [0,384)
    const int i = t >> 7;                             // bin
    const int rem = t & 127;
    const int ob = (rem >> 3) * 32, cb = (rem & 7) * 64;
    const int tx = tid & 15, ty = tid >> 4;
    float acc[2][4] = {};
    for (int kt = 0; kt < 512; kt += 16) {
      __syncthreads();
      if (tid < 128) {
        int o = tid >> 2, e4 = (tid & 3) * 4;
        float4 a4 = *(const float4*)&Ws1[(size_t)(ob + o) * 1536 + i * 512 + kt + e4];
        As[e4 + 0][o] = a4.x; As[e4 + 1][o] = a4.y;
        As[e4 + 2][o] = a4.z; As[e4 + 3][o] = a4.w;
      }
      {
        int e = tid & 15, c4 = (tid >> 4) * 4;
        float4 b4 = *(const float4*)&Wa[((size_t)i << 18) + (size_t)(kt + e) * 512 + cb + c4];
        *(float4*)&Bs[e][c4] = b4;
      }
      __syncthreads();
#pragma unroll
      for (int k = 0; k < 16; ++k) {
        float a0 = As[k][ty * 2], a1 = As[k][ty * 2 + 1];
        float bb[4];
        *(float4*)bb = *(const float4*)&Bs[k][tx * 4];
#pragma unroll
        for (int c = 0; c < 4; ++c) {
          acc[0][c] += a0 * bb[c];
          acc[1][c] += a1 * bb[c];
        }
      }
    }
#pragma unroll
    for (int rr = 0; rr < 2; ++rr)
#pragma unroll
      for (int c = 0; c < 4; ++c)
        Wcatb[(size_t)(ob + ty * 2 + rr) * 1536 + i * 512 + cb + tx * 4 + c] =
            f2bf(acc[rr][c]);
    return;
  }
  if (blk < 9728) {                                   // bcomb: wave per o
    const int o = (blk - 9600) * 4 + (tid >> 6);
    const int lane = tid & 63;
    const float* row = Ws1 + (size_t)o * 1536;
    float s = 0.f;
#pragma unroll
    for (int c0 = 0; c0 < 1536; c0 += 256) {
      s += row[c0 + lane] * ba[c0 + lane];
      s += row[c0 + 64 + lane] * ba[c0 + 64 + lane];
      s += row[c0 + 128 + lane] * ba[c0 + 128 + lane];
      s += row[c0 + 192 + lane] * ba[c0 + 192 + lane];
    }
#pragma unroll
    for (int off = 32; off > 0; off >>= 1) s += __shfl_xor(s, off);
    if (lane == 0) bcomb[o] = bs1[o] + s;
    return;
  }
  if (blk < 9729) {                                   // bqkv concat
    for (int i = tid; i < 1536; i += 256)
      bqkv[i] = (i < 512) ? bq[i] : (i < 1024) ? bk[i - 512] : bv[i - 1024];
    return;
  }
  {                                                   // keep-bits
    const int gw = (blk - 9729) * 4 + (tid >> 6);
    const int lane = tid & 63;
    const int b = gw >> 8, row = gw & 255;
    const float cut0 = dist_bar[b * 3 + 0];
    const float cut1 = dist_bar[b * 3 + 1];
    const float cut2 = dist_bar[b * 3 + 2];
    const float* mrow = maskg + (size_t)b * 65536 + (size_t)row * 256;
    const int rj = (row == 0) ? 1 : row;
    const float* drow = dist + (size_t)b * 65025 + (size_t)(rj - 1) * 255;
    unsigned long long* out = bits + (size_t)gw * 12;
#pragma unroll
    for (int cc = 0; cc < 4; ++cc) {
      const int col = cc * 64 + lane;
      const int cj = (col == 0) ? 1 : col;
      float dv = drow[cj - 1];
      bool sup = (row == 0) || (col == 0);
      bool mk = (mrow[col] != 0.f);
      if (sup) dv = -1e30f;
      unsigned long long b0 = __ballot(mk && (dv < cut0));
      unsigned long long b1 = __ballot(mk && (dv < cut1));
      unsigned long long b2 = __ballot(mk && (dv < cut2));
      if (lane == 0) { out[cc] = b0; out[4 + cc] = b1; out[8 + cc] = b2; }
    }
  }
}

// ---------------------------------------------------------------------------
// bf16 MFMA NT GEMM, 2-phase double-buffered; BM in {64,128}.
// BM=64 -> 4 waves across N (per-wave 64x32, acc[4][2], ~half VGPR/LDS) for
// occupancy-limited shapes; BM=128 -> classic 2x2 wave grid.
template <int ACT, int RES, int OBF, int BK, int SQ, int BM>
__global__ __launch_bounds__(256) void msa_gemm_mfma(
    const unsigned short* __restrict__ A, int lda,
    const unsigned short* __restrict__ W, int ldw,
    const float* __restrict__ bias, const float* __restrict__ resid,
    void* __restrict__ Cout, int ldc, int Kdim) {
  constexpr int KSUB = BK / 32;
  constexpr int RPC = BK / 8;                 // 16B chunks per row
  constexpr int CPTA = (BM * RPC) / 256;
  constexpr int CPTB = (128 * RPC) / 256;
  constexpr int WC = (BM == 128) ? 2 : 4;     // waves across N
  constexpr int NFR = 8 / WC;                 // n-fragments per wave
  constexpr int NW = 16 * NFR;                // n-columns per wave
  __shared__ __align__(16) unsigned short Asm_[2][BM * BK];
  __shared__ __align__(16) unsigned short Bsm_[2][128 * BK];
  const int tid = threadIdx.x;
  const int lane = tid & 63, wv = tid >> 6;
  const int m0 = blockIdx.x * BM, n0 = blockIdx.y * 128;
  const int wr = wv / WC, wc = wv % WC;
  const int fr = lane & 15, fq = lane >> 4;
  f32x4 acc[4][NFR] = {};
  const unsigned short* Ag[CPTA];
  const unsigned short* Wg[CPTB];
#pragma unroll
  for (int i = 0; i < CPTA; ++i) {
    int c = tid + i * 256;
    int row = c / RPC, j = c % RPC;
    Ag[i] = A + (size_t)(m0 + row) * lda + j * 8;
  }
#pragma unroll
  for (int i = 0; i < CPTB; ++i) {
    int c = tid + i * 256;
    int row = c / RPC, j = c % RPC;
    Wg[i] = W + (size_t)(n0 + row) * ldw + j * 8;
  }
#pragma unroll
  for (int i = 0; i < CPTA; ++i) GLDS16(Ag[i], &Asm_[0][(tid + i * 256) * 8]);
#pragma unroll
  for (int i = 0; i < CPTB; ++i) GLDS16(Wg[i], &Bsm_[0][(tid + i * 256) * 8]);
  __syncthreads();
  int cur = 0;
  for (int kt = 0; kt < Kdim; kt += BK) {
    if (kt + BK < Kdim) {
      const int nx = cur ^ 1, k2 = kt + BK;
#pragma unroll
      for (int i = 0; i < CPTA; ++i) GLDS16(Ag[i] + k2, &Asm_[nx][(tid + i * 256) * 8]);
#pragma unroll
      for (int i = 0; i < CPTB; ++i) GLDS16(Wg[i] + k2, &Bsm_[nx][(tid + i * 256) * 8]);
    }
#pragma unroll
    for (int ks = 0; ks < KSUB; ++ks) {
      bf16x8 af[4], bfr[NFR];
#pragma unroll
      for (int mf = 0; mf < 4; ++mf)
        af[mf] = *(const bf16x8*)&Asm_[cur][(wr * 64 + mf * 16 + fr) * BK + ks * 32 + fq * 8];
#pragma unroll
      for (int nf = 0; nf < NFR; ++nf)
        bfr[nf] = *(const bf16x8*)&Bsm_[cur][(wc * NW + nf * 16 + fr) * BK + ks * 32 + fq * 8];
#pragma unroll
      for (int mf = 0; mf < 4; ++mf)
#pragma unroll
        for (int nf = 0; nf < NFR; ++nf)
          acc[mf][nf] = __builtin_amdgcn_mfma_f32_16x16x32_bf16(
              af[mf], bfr[nf], acc[mf][nf], 0, 0, 0);
    }
    __syncthreads();
    cur ^= 1;
  }
#pragma unroll
  for (int mf = 0; mf < 4; ++mf) {
#pragma unroll
    for (int nf = 0; nf < NFR; ++nf) {
      const int n = n0 + wc * NW + nf * 16 + fr;
      const float bval = bias[n];
#pragma unroll
      for (int r = 0; r < 4; ++r) {
        const int m = m0 + wr * 64 + mf * 16 + fq * 4 + r;
        float val = acc[mf][nf][r] + bval;
        if (SQ == 1 && n < 512) val *= 0.125f;        // fold 1/sqrt(dk) into q
        if (ACT == 1) val = val / (1.f + __expf(-val));
        if (RES == 1) val += resid[(size_t)m * ldc + n];
        if (OBF == 1)
          ((unsigned short*)Cout)[(size_t)m * ldc + n] = f2bf(val);
        else
          ((float*)Cout)[(size_t)m * ldc + n] = val;
      }
    }
  }
}

// ---------------------------------------------------------------------------
// Fused attention (swapped QK^T; q pre-scaled; NT stores; trailing LDS drain
// removed — per-wave DS ops are in-order so WAR on Pl is safe)
__global__ __launch_bounds__(512) void msa_fused(
    const unsigned short* __restrict__ qkvb,
    const unsigned long long* __restrict__ bits,
    float* __restrict__ attn_out, unsigned short* __restrict__ mob) {
  const int blk = blockIdx.x;
  const int b = (blk & 7) * 8 + (blk >> 6);   // bijective on [0,512)
  const int h = (blk >> 3) & 7;
  __shared__ __align__(16) unsigned short Kl[256][72];     // 36864 B
  __shared__ __align__(16) unsigned short Vt[64][264];     // 33792 B
  __shared__ __align__(16) unsigned short Pl[8][16][256];  // 65536 B
  const int tid = threadIdx.x;
  const int wv = tid >> 6, lane = tid & 63;
  const int l15 = lane & 15, fq = lane >> 4;
  // --- stage K ---
  {
    const unsigned short* kgp = qkvb + (size_t)(b * 256) * 1536 + 512 + h * 64;
#pragma unroll
    for (int i = 0; i < 4; ++i) {
      int s = tid + i * 512;
      int row = s >> 3, c8 = (s & 7) << 3;
      *(uint4*)&Kl[row][c8] = *(const uint4*)&kgp[(size_t)row * 1536 + c8];
    }
  }
  // --- stage V transposed ---
  {
    int rv = tid & 255, half = tid >> 8;
    const unsigned short* vgp =
        qkvb + (size_t)(b * 256 + rv) * 1536 + 1024 + h * 64 + half * 32;
#pragma unroll
    for (int j4 = 0; j4 < 4; ++j4) {
      unsigned short tmp[8];
      *(uint4*)tmp = *(const uint4*)&vgp[j4 * 8];
#pragma unroll
      for (int j = 0; j < 8; ++j) Vt[half * 32 + j4 * 8 + j][rv] = tmp[j];
    }
  }
  __syncthreads();
  char* plbase = (char*)&Pl[wv][0][0];
  const int swz = ((l15 & 1) << 6) | ((l15 & 2) << 4);
#pragma unroll
  for (int mf = 0; mf < 2; ++mf) {
    const int r0 = wv * 32 + mf * 16;
    const int q = r0 + l15;
    const unsigned short* qgp =
        qkvb + (size_t)(b * 256 + q) * 1536 + h * 64 + fq * 8;
    bf16x8 aq0 = *(const bf16x8*)qgp;
    bf16x8 aq1 = *(const bf16x8*)(qgp + 32);
    f32x4 accs[16];
#pragma unroll
    for (int nt = 0; nt < 16; ++nt) {
      bf16x8 bk0 = *(const bf16x8*)&Kl[nt * 16 + l15][fq * 8];
      bf16x8 bk1 = *(const bf16x8*)&Kl[nt * 16 + l15][32 + fq * 8];
      f32x4 a = {};
      a = __builtin_amdgcn_mfma_f32_16x16x32_bf16(bk0, aq0, a, 0, 0, 0);  // swapped
      a = __builtin_amdgcn_mfma_f32_16x16x32_bf16(bk1, aq1, a, 0, 0, 0);
      accs[nt] = a;
    }
    const unsigned long long* brow = bits + (size_t)(b * 256 + q) * 12;
#pragma unroll
    for (int bin = 0; bin < 3; ++bin) {
      const unsigned long long w0 = brow[bin * 4 + 0];
      const unsigned long long w1 = brow[bin * 4 + 1];
      const unsigned long long w2 = brow[bin * 4 + 2];
      const unsigned long long w3 = brow[bin * 4 + 3];
      f32x4 p[16];
      float m = -3e38f;
#pragma unroll
      for (int nt = 0; nt < 16; ++nt) {
        unsigned long long w = (nt < 4) ? w0 : (nt < 8) ? w1 : (nt < 12) ? w2 : w3;
#pragma unroll
        for (int r = 0; r < 4; ++r) {
          unsigned keep = (unsigned)(w >> (16 * (nt & 3) + 4 * fq + r)) & 1u;
          float sv = accs[nt][r];
          float v = keep ? sv : NEGV;
          p[nt][r] = v;
          m = fmaxf(m, v);
        }
      }
      m = fmaxf(m, __shfl_xor(m, 16));
      m = fmaxf(m, __shfl_xor(m, 32));
      float sum = 0.f;
#pragma unroll
      for (int nt = 0; nt < 16; ++nt)
#pragma unroll
        for (int r = 0; r < 4; ++r) {
          p[nt][r] = __expf(p[nt][r] - m);
          sum += p[nt][r];
        }
      sum += __shfl_xor(sum, 16);
      sum += __shfl_xor(sum, 32);
      const float inv = 1.f / sum;
      float* prow = attn_out + ((size_t)((bin * 64 + b) * 8 + h)) * 65536 +
                    (size_t)q * 256;
#pragma unroll
      for (int nt = 0; nt < 16; ++nt) {
        float v0 = p[nt][0] * inv, v1 = p[nt][1] * inv;
        float v2 = p[nt][2] * inv, v3 = p[nt][3] * inv;
        f32x4 st = {v0, v1, v2, v3};
        __builtin_nontemporal_store(st, (f32x4*)(prow + nt * 16 + fq * 4));
        unsigned short u[4];
        u[0] = f2bf(v0); u[1] = f2bf(v1); u[2] = f2bf(v2); u[3] = f2bf(v3);
        int wb = (l15 << 9) | (nt << 5) | (fq << 3);
        *(uint2*)(plbase + (wb ^ swz)) = *(const uint2*)u;
      }
      asm volatile("s_waitcnt lgkmcnt(0)" ::: "memory");
      __builtin_amdgcn_sched_barrier(0);
      f32x4 acco[4] = {};
#pragma unroll
      for (int c = 0; c < 8; ++c) {
        int rb = (l15 << 9) | (c << 6) | (fq << 4);
        bf16x8 pa = *(const bf16x8*)(plbase + (rb ^ swz));
#pragma unroll
        for (int nf = 0; nf < 4; ++nf) {
          bf16x8 bv = *(const bf16x8*)&Vt[nf * 16 + l15][c * 32 + fq * 8];
          acco[nf] = __builtin_amdgcn_mfma_f32_16x16x32_bf16(pa, bv, acco[nf], 0, 0, 0);
        }
      }
#pragma unroll
      for (int nf = 0; nf < 4; ++nf)
#pragma unroll
        for (int r = 0; r < 4; ++r)
          mob[((size_t)(b * 256 + r0 + fq * 4 + r) * 3 + bin) * 512 +
              h * 64 + nf * 16 + l15] = f2bf(acco[nf][r]);
      // no trailing LDS drain: per-wave DS in-order guarantees WAR safety
    }
  }
}

// ---------------------------------------------------------------------------
// Fused mlp2 + residual + LayerNorm (residual now from bf16 xb)
__global__ __launch_bounds__(256) void msa_mlp2ln(
    const unsigned short* __restrict__ h1b, const unsigned short* __restrict__ Ws2b,
    const float* __restrict__ bs2, const unsigned short* __restrict__ xb,
    const float* __restrict__ gamma, const float* __restrict__ beta,
    float* __restrict__ outp) {
  __shared__ __align__(16) unsigned short Al[32 * 32];
  __shared__ __align__(16) unsigned short Bl[512 * 32];
  __shared__ float red[2][2][32];
  const int tid = threadIdx.x;
  const int lane = tid & 63, wv = tid >> 6;
  const int wr = wv >> 1, wc = wv & 1;
  const int l15 = lane & 15, fq = lane >> 4;
  const int m0 = blockIdx.x * 32;
  f32x4 acc[16] = {};
  for (int kt = 0; kt < 512; kt += 32) {
    if (tid < 128) {
      int row = tid >> 2, c8 = (tid & 3) * 8;
      GLDS16(h1b + (size_t)(m0 + row) * 512 + kt + c8, &Al[tid * 8]);
    }
#pragma unroll
    for (int i = 0; i < 8; ++i) {
      int c = tid + i * 256;
      int row = c >> 2, c8 = (c & 3) * 8;
      GLDS16(Ws2b + (size_t)row * 512 + kt + c8, &Bl[c * 8]);
    }
    __syncthreads();
    bf16x8 af = *(const bf16x8*)&Al[(wr * 16 + l15) * 32 + fq * 8];
#pragma unroll
    for (int nt = 0; nt < 16; ++nt) {
      bf16x8 bfr = *(const bf16x8*)&Bl[(wc * 256 + nt * 16 + l15) * 32 + fq * 8];
      acc[nt] = __builtin_amdgcn_mfma_f32_16x16x32_bf16(af, bfr, acc[nt], 0, 0, 0);
    }
    __syncthreads();
  }
  float vals[16][4];
#pragma unroll
  for (int nt = 0; nt < 16; ++nt) {
    const int n = wc * 256 + nt * 16 + l15;
    const float bval = bs2[n];
#pragma unroll
    for (int r = 0; r < 4; ++r) {
      const int m = m0 + wr * 16 + fq * 4 + r;
      vals[nt][r] = acc[nt][r] + bval + bf2f(xb[(size_t)m * 512 + n]);
    }
  }
  const int ridx = wr * 16 + fq * 4;
#pragma unroll
  for (int r = 0; r < 4; ++r) {
    float s = 0.f;
#pragma unroll
    for (int nt = 0; nt < 16; ++nt) s += vals[nt][r];
    s += __shfl_xor(s, 1); s += __shfl_xor(s, 2);
    s += __shfl_xor(s, 4); s += __shfl_xor(s, 8);
    if (l15 == 0) red[0][wc][ridx + r] = s;
  }
  __syncthreads();
  float mu[4];
#pragma unroll
  for (int r = 0; r < 4; ++r)
    mu[r] = (red[0][0][ridx + r] + red[0][1][ridx + r]) * (1.f / 512.f);
#pragma unroll
  for (int r = 0; r < 4; ++r) {
    float s = 0.f;
#pragma unroll
    for (int nt = 0; nt < 16; ++nt) {
      float d = vals[nt][r] - mu[r];
      s += d * d;
    }
    s += __shfl_xor(s, 1); s += __shfl_xor(s, 2);
    s += __shfl_xor(s, 4); s += __shfl_xor(s, 8);
    if (l15 == 0) red[1][wc][ridx + r] = s;
  }
  __syncthreads();
  float iv[4];
#pragma unroll
  for (int r = 0; r < 4; ++r) {
    float var = (red[1][0][ridx + r] + red[1][1][ridx + r]) * (1.f / 512.f);
    iv[r] = 1.f / sqrtf(var + 1e-6f);
  }
#pragma unroll
  for (int nt = 0; nt < 16; ++nt) {
    const int n = wc * 256 + nt * 16 + l15;
    const float g = gamma[n], be = beta[n];
#pragma unroll
    for (int r = 0; r < 4; ++r) {
      const int m = m0 + wr * 16 + fq * 4 + r;
      outp[(size_t)m * 512 + n] = (vals[nt][r] - mu[r]) * iv[r] * g + be;
    }
  }
}

// ---------------------------------------------------------------------------
extern "C" void kernel_launch(void* const* d_in, const int* in_sizes, int n_in,
                              void* d_out, int out_size, void* d_ws, size_t ws_size,
                              hipStream_t stream) {
  (void)in_sizes; (void)n_in; (void)out_size; (void)ws_size;
  const float* x        = (const float*)d_in[0];
  const float* dist     = (const float*)d_in[1];
  const float* dist_bar = (const float*)d_in[2];
  const float* mask     = (const float*)d_in[3];
  const float* Wq  = (const float*)d_in[4];  const float* bq  = (const float*)d_in[5];
  const float* Wk  = (const float*)d_in[6];  const float* bk  = (const float*)d_in[7];
  const float* Wv  = (const float*)d_in[8];  const float* bv  = (const float*)d_in[9];
  const float* Wa  = (const float*)d_in[10]; const float* ba  = (const float*)d_in[11];
  const float* Ws1 = (const float*)d_in[12]; const float* bs1 = (const float*)d_in[13];
  const float* Ws2 = (const float*)d_in[14]; const float* bs2 = (const float*)d_in[15];
  const float* gamma = (const float*)d_in[16]; const float* beta = (const float*)d_in[17];

  char* w8 = (char*)d_ws;
  const size_t SZ = 8388608;                         // 16384*512
  unsigned short* qkvb = (unsigned short*)(w8 + 0);            // 50.3 MB [16384][1536]
  unsigned short* mob  = (unsigned short*)(w8 + 50331648);     // 50.3 MB [16384][1536]
  unsigned short* xb   = (unsigned short*)(w8 + 100663296);    // 16.8 MB
  unsigned short* Wqkvb= (unsigned short*)(w8 + 117440512);    // 1.6 MB [1536][512]
  unsigned short* Ws2b = (unsigned short*)(w8 + 119013376);    // 0.5 MB
  unsigned short* Wcatb= (unsigned short*)(w8 + 119537664);    // 1.6 MB [512][1536]
  float* bcomb = (float*)(w8 + 121110528);                     // 2 KB
  float* bqkv  = (float*)(w8 + 121112576);                     // 6 KB
  unsigned long long* bits = (unsigned long long*)(w8 + 121118720);  // 1.6 MB
  unsigned short* h1b = qkvb;                        // qkvb dead after msa_fused
  float* outp = (float*)d_out;
  float* attn = outp + SZ;                           // [3,B,8,256,256] fp32

  msa_prep<<<13825, 256, 0, stream>>>(x, Wq, Wk, Wv, Ws2, Ws1, Wa, bq, bk, bv,
                                      ba, bs1, dist, dist_bar, mask,
                                      xb, Wqkvb, Ws2b, Wcatb, bcomb, bqkv, bits);

  // qkv = x @ [Wq;Wk;Wv]^T + bqkv  (q columns pre-scaled by 0.125)
  msa_gemm_mfma<0, 0, 1, 32, 1, 128><<<dim3(128, 12), 256, 0, stream>>>(
      xb, 512, Wqkvb, 512, bqkv, nullptr, qkvb, 1536, 512);

  msa_fused<<<512, 512, 0, stream>>>(qkvb, bits, attn, mob);

  // h1b = silu(mob @ Wcatb^T + bcomb)  [BM=64 tile -> 1024 blocks, 4/CU]
  msa_gemm_mfma<1, 0, 1, 32, 0, 64><<<dim3(256, 4), 256, 0, stream>>>(
      mob, 1536, Wcatb, 1536, bcomb, nullptr, h1b, 512, 1536);

  // out = LN(h1b @ Ws2b^T + bs2 + xb) * gamma + beta
  msa_mlp2ln<<<512, 256, 0, stream>>>(h1b, Ws2b, bs2, xb, gamma, beta, outp);
}

// Round 14
// 305.176 us; speedup vs baseline: 1.0659x; 1.0057x over previous
//
#include <hip/hip_runtime.h>
#include <cstddef>

#define NEGV (-1e12f)

// Sizes (fixed): B=64, N=256, H=512, HEADS=8, DK=64, NBINS=3

typedef __attribute__((ext_vector_type(4))) float f32x4;
typedef __attribute__((ext_vector_type(8))) __bf16 bf16x8;

__device__ __forceinline__ unsigned short f2bf(float f) {
  union { float f; unsigned u; } v; v.f = f;
  unsigned r = v.u + 0x7FFFu + ((v.u >> 16) & 1u);   // round-nearest-even
  return (unsigned short)(r >> 16);
}
__device__ __forceinline__ float bf2f(unsigned short u) {
  union { unsigned u; float f; } v; v.u = (unsigned)u << 16; return v.f;
}

#define GLDS16(gp, lp)                                                      \
  __builtin_amdgcn_global_load_lds(                                         \
      (const __attribute__((address_space(1))) void*)(gp),                  \
      (__attribute__((address_space(3))) void*)(lp), 16, 0, 0)

// ---------------------------------------------------------------------------
// Mega-prep (unchanged)
__global__ __launch_bounds__(256) void msa_prep(
    const float* __restrict__ x, const float* __restrict__ Wq,
    const float* __restrict__ Wk, const float* __restrict__ Wv,
    const float* __restrict__ Ws2, const float* __restrict__ Ws1,
    const float* __restrict__ Wa, const float* __restrict__ bq,
    const float* __restrict__ bk, const float* __restrict__ bv,
    const float* __restrict__ ba, const float* __restrict__ bs1,
    const float* __restrict__ dist, const float* __restrict__ dist_bar,
    const float* __restrict__ maskg,
    unsigned short* __restrict__ xb, unsigned short* __restrict__ Wqkvb,
    unsigned short* __restrict__ Ws2b, unsigned short* __restrict__ Wcatb,
    float* __restrict__ bcomb, float* __restrict__ bqkv,
    unsigned long long* __restrict__ bits) {
  __shared__ float As[16][36];
  __shared__ float Bs[16][68];
  const int blk = blockIdx.x;
  const int tid = threadIdx.x;
  if (blk < 8192) {                                   // xb
    int i = blk * 256 + tid;
    float4 v = ((const float4*)x)[i];
    ushort4 o; o.x = f2bf(v.x); o.y = f2bf(v.y); o.z = f2bf(v.z); o.w = f2bf(v.w);
    ((ushort4*)xb)[i] = o;
    return;
  }
  if (blk < 8960) {                                   // weight f2b
    int sel = (blk - 8192) >> 8;                      // 0..2
    int i = ((blk - 8192) & 255) * 256 + tid;
    const float* src = (sel == 0) ? Wq : (sel == 1) ? Wk : Wv;
    unsigned short* dst = Wqkvb + (size_t)sel * 262144;
    float4 v = ((const float4*)src)[i];
    ushort4 o; o.x = f2bf(v.x); o.y = f2bf(v.y); o.z = f2bf(v.z); o.w = f2bf(v.w);
    ((ushort4*)dst)[i] = o;
    return;
  }
  if (blk < 9216) {                                   // Ws2b
    int i = (blk - 8960) * 256 + tid;
    float4 v = ((const float4*)Ws2)[i];
    ushort4 o; o.x = f2bf(v.x); o.y = f2bf(v.y); o.z = f2bf(v.z); o.w = f2bf(v.w);
    ((ushort4*)Ws2b)[i] = o;
    return;
  }
  if (blk < 9600) {                                   // Wcat 32x64 tile
    const int t = blk - 9216;                         // [0,384)
    const int i = t >> 7;                             // bin
    const int rem = t & 127;
    const int ob = (rem >> 3) * 32, cb = (rem & 7) * 64;
    const int tx = tid & 15, ty = tid >> 4;
    float acc[2][4] = {};
    for (int kt = 0; kt < 512; kt += 16) {
      __syncthreads();
      if (tid < 128) {
        int o = tid >> 2, e4 = (tid & 3) * 4;
        float4 a4 = *(const float4*)&Ws1[(size_t)(ob + o) * 1536 + i * 512 + kt + e4];
        As[e4 + 0][o] = a4.x; As[e4 + 1][o] = a4.y;
        As[e4 + 2][o] = a4.z; As[e4 + 3][o] = a4.w;
      }
      {
        int e = tid & 15, c4 = (tid >> 4) * 4;
        float4 b4 = *(const float4*)&Wa[((size_t)i << 18) + (size_t)(kt + e) * 512 + cb + c4];
        *(float4*)&Bs[e][c4] = b4;
      }
      __syncthreads();
#pragma unroll
      for (int k = 0; k < 16; ++k) {
        float a0 = As[k][ty * 2], a1 = As[k][ty * 2 + 1];
        float bb[4];
        *(float4*)bb = *(const float4*)&Bs[k][tx * 4];
#pragma unroll
        for (int c = 0; c < 4; ++c) {
          acc[0][c] += a0 * bb[c];
          acc[1][c] += a1 * bb[c];
        }
      }
    }
#pragma unroll
    for (int rr = 0; rr < 2; ++rr)
#pragma unroll
      for (int c = 0; c < 4; ++c)
        Wcatb[(size_t)(ob + ty * 2 + rr) * 1536 + i * 512 + cb + tx * 4 + c] =
            f2bf(acc[rr][c]);
    return;
  }
  if (blk < 9728) {                                   // bcomb: wave per o
    const int o = (blk - 9600) * 4 + (tid >> 6);
    const int lane = tid & 63;
    const float* row = Ws1 + (size_t)o * 1536;
    float s = 0.f;
#pragma unroll
    for (int c0 = 0; c0 < 1536; c0 += 256) {
      s += row[c0 + lane] * ba[c0 + lane];
      s += row[c0 + 64 + lane] * ba[c0 + 64 + lane];
      s += row[c0 + 128 + lane] * ba[c0 + 128 + lane];
      s += row[c0 + 192 + lane] * ba[c0 + 192 + lane];
    }
#pragma unroll
    for (int off = 32; off > 0; off >>= 1) s += __shfl_xor(s, off);
    if (lane == 0) bcomb[o] = bs1[o] + s;
    return;
  }
  if (blk < 9729) {                                   // bqkv concat
    for (int i = tid; i < 1536; i += 256)
      bqkv[i] = (i < 512) ? bq[i] : (i < 1024) ? bk[i - 512] : bv[i - 1024];
    return;
  }
  {                                                   // keep-bits
    const int gw = (blk - 9729) * 4 + (tid >> 6);
    const int lane = tid & 63;
    const int b = gw >> 8, row = gw & 255;
    const float cut0 = dist_bar[b * 3 + 0];
    const float cut1 = dist_bar[b * 3 + 1];
    const float cut2 = dist_bar[b * 3 + 2];
    const float* mrow = maskg + (size_t)b * 65536 + (size_t)row * 256;
    const int rj = (row == 0) ? 1 : row;
    const float* drow = dist + (size_t)b * 65025 + (size_t)(rj - 1) * 255;
    unsigned long long* out = bits + (size_t)gw * 12;
#pragma unroll
    for (int cc = 0; cc < 4; ++cc) {
      const int col = cc * 64 + lane;
      const int cj = (col == 0) ? 1 : col;
      float dv = drow[cj - 1];
      bool sup = (row == 0) || (col == 0);
      bool mk = (mrow[col] != 0.f);
      if (sup) dv = -1e30f;
      unsigned long long b0 = __ballot(mk && (dv < cut0));
      unsigned long long b1 = __ballot(mk && (dv < cut1));
      unsigned long long b2 = __ballot(mk && (dv < cut2));
      if (lane == 0) { out[cc] = b0; out[4 + cc] = b1; out[8 + cc] = b2; }
    }
  }
}

// ---------------------------------------------------------------------------
// bf16 MFMA NT GEMM (unchanged from round 13)
template <int ACT, int RES, int OBF, int BK, int SQ, int BM>
__global__ __launch_bounds__(256) void msa_gemm_mfma(
    const unsigned short* __restrict__ A, int lda,
    const unsigned short* __restrict__ W, int ldw,
    const float* __restrict__ bias, const float* __restrict__ resid,
    void* __restrict__ Cout, int ldc, int Kdim) {
  constexpr int KSUB = BK / 32;
  constexpr int RPC = BK / 8;
  constexpr int CPTA = (BM * RPC) / 256;
  constexpr int CPTB = (128 * RPC) / 256;
  constexpr int WC = (BM == 128) ? 2 : 4;
  constexpr int NFR = 8 / WC;
  constexpr int NW = 16 * NFR;
  __shared__ __align__(16) unsigned short Asm_[2][BM * BK];
  __shared__ __align__(16) unsigned short Bsm_[2][128 * BK];
  const int tid = threadIdx.x;
  const int lane = tid & 63, wv = tid >> 6;
  const int m0 = blockIdx.x * BM, n0 = blockIdx.y * 128;
  const int wr = wv / WC, wc = wv % WC;
  const int fr = lane & 15, fq = lane >> 4;
  f32x4 acc[4][NFR] = {};
  const unsigned short* Ag[CPTA];
  const unsigned short* Wg[CPTB];
#pragma unroll
  for (int i = 0; i < CPTA; ++i) {
    int c = tid + i * 256;
    int row = c / RPC, j = c % RPC;
    Ag[i] = A + (size_t)(m0 + row) * lda + j * 8;
  }
#pragma unroll
  for (int i = 0; i < CPTB; ++i) {
    int c = tid + i * 256;
    int row = c / RPC, j = c % RPC;
    Wg[i] = W + (size_t)(n0 + row) * ldw + j * 8;
  }
#pragma unroll
  for (int i = 0; i < CPTA; ++i) GLDS16(Ag[i], &Asm_[0][(tid + i * 256) * 8]);
#pragma unroll
  for (int i = 0; i < CPTB; ++i) GLDS16(Wg[i], &Bsm_[0][(tid + i * 256) * 8]);
  __syncthreads();
  int cur = 0;
  for (int kt = 0; kt < Kdim; kt += BK) {
    if (kt + BK < Kdim) {
      const int nx = cur ^ 1, k2 = kt + BK;
#pragma unroll
      for (int i = 0; i < CPTA; ++i) GLDS16(Ag[i] + k2, &Asm_[nx][(tid + i * 256) * 8]);
#pragma unroll
      for (int i = 0; i < CPTB; ++i) GLDS16(Wg[i] + k2, &Bsm_[nx][(tid + i * 256) * 8]);
    }
#pragma unroll
    for (int ks = 0; ks < KSUB; ++ks) {
      bf16x8 af[4], bfr[NFR];
#pragma unroll
      for (int mf = 0; mf < 4; ++mf)
        af[mf] = *(const bf16x8*)&Asm_[cur][(wr * 64 + mf * 16 + fr) * BK + ks * 32 + fq * 8];
#pragma unroll
      for (int nf = 0; nf < NFR; ++nf)
        bfr[nf] = *(const bf16x8*)&Bsm_[cur][(wc * NW + nf * 16 + fr) * BK + ks * 32 + fq * 8];
#pragma unroll
      for (int mf = 0; mf < 4; ++mf)
#pragma unroll
        for (int nf = 0; nf < NFR; ++nf)
          acc[mf][nf] = __builtin_amdgcn_mfma_f32_16x16x32_bf16(
              af[mf], bfr[nf], acc[mf][nf], 0, 0, 0);
    }
    __syncthreads();
    cur ^= 1;
  }
#pragma unroll
  for (int mf = 0; mf < 4; ++mf) {
#pragma unroll
    for (int nf = 0; nf < NFR; ++nf) {
      const int n = n0 + wc * NW + nf * 16 + fr;
      const float bval = bias[n];
#pragma unroll
      for (int r = 0; r < 4; ++r) {
        const int m = m0 + wr * 64 + mf * 16 + fq * 4 + r;
        float val = acc[mf][nf][r] + bval;
        if (SQ == 1 && n < 512) val *= 0.125f;        // fold 1/sqrt(dk) into q
        if (ACT == 1) val = val / (1.f + __expf(-val));
        if (RES == 1) val += resid[(size_t)m * ldc + n];
        if (OBF == 1)
          ((unsigned short*)Cout)[(size_t)m * ldc + n] = f2bf(val);
        else
          ((float*)Cout)[(size_t)m * ldc + n] = val;
      }
    }
  }
}

// ---------------------------------------------------------------------------
// Fused attention: swapped QK^T; tree-ified softmax reductions (4 independent
// chains for max and sum instead of 64-deep serial); setprio around MFMA.
__global__ __launch_bounds__(512) void msa_fused(
    const unsigned short* __restrict__ qkvb,
    const unsigned long long* __restrict__ bits,
    float* __restrict__ attn_out, unsigned short* __restrict__ mob) {
  const int blk = blockIdx.x;
  const int b = (blk & 7) * 8 + (blk >> 6);   // bijective on [0,512)
  const int h = (blk >> 3) & 7;
  __shared__ __align__(16) unsigned short Kl[256][72];     // 36864 B
  __shared__ __align__(16) unsigned short Vt[64][264];     // 33792 B
  __shared__ __align__(16) unsigned short Pl[8][16][256];  // 65536 B
  const int tid = threadIdx.x;
  const int wv = tid >> 6, lane = tid & 63;
  const int l15 = lane & 15, fq = lane >> 4;
  // --- stage K ---
  {
    const unsigned short* kgp = qkvb + (size_t)(b * 256) * 1536 + 512 + h * 64;
#pragma unroll
    for (int i = 0; i < 4; ++i) {
      int s = tid + i * 512;
      int row = s >> 3, c8 = (s & 7) << 3;
      *(uint4*)&Kl[row][c8] = *(const uint4*)&kgp[(size_t)row * 1536 + c8];
    }
  }
  // --- stage V transposed ---
  {
    int rv = tid & 255, half = tid >> 8;
    const unsigned short* vgp =
        qkvb + (size_t)(b * 256 + rv) * 1536 + 1024 + h * 64 + half * 32;
#pragma unroll
    for (int j4 = 0; j4 < 4; ++j4) {
      unsigned short tmp[8];
      *(uint4*)tmp = *(const uint4*)&vgp[j4 * 8];
#pragma unroll
      for (int j = 0; j < 8; ++j) Vt[half * 32 + j4 * 8 + j][rv] = tmp[j];
    }
  }
  __syncthreads();
  char* plbase = (char*)&Pl[wv][0][0];
  const int swz = ((l15 & 1) << 6) | ((l15 & 2) << 4);
#pragma unroll
  for (int mf = 0; mf < 2; ++mf) {
    const int r0 = wv * 32 + mf * 16;
    const int q = r0 + l15;
    const unsigned short* qgp =
        qkvb + (size_t)(b * 256 + q) * 1536 + h * 64 + fq * 8;
    bf16x8 aq0 = *(const bf16x8*)qgp;
    bf16x8 aq1 = *(const bf16x8*)(qgp + 32);
    f32x4 accs[16];
    __builtin_amdgcn_s_setprio(1);
#pragma unroll
    for (int nt = 0; nt < 16; ++nt) {
      bf16x8 bk0 = *(const bf16x8*)&Kl[nt * 16 + l15][fq * 8];
      bf16x8 bk1 = *(const bf16x8*)&Kl[nt * 16 + l15][32 + fq * 8];
      f32x4 a = {};
      a = __builtin_amdgcn_mfma_f32_16x16x32_bf16(bk0, aq0, a, 0, 0, 0);  // swapped
      a = __builtin_amdgcn_mfma_f32_16x16x32_bf16(bk1, aq1, a, 0, 0, 0);
      accs[nt] = a;
    }
    __builtin_amdgcn_s_setprio(0);
    const unsigned long long* brow = bits + (size_t)(b * 256 + q) * 12;
#pragma unroll
    for (int bin = 0; bin < 3; ++bin) {
      const unsigned long long w0 = brow[bin * 4 + 0];
      const unsigned long long w1 = brow[bin * 4 + 1];
      const unsigned long long w2 = brow[bin * 4 + 2];
      const unsigned long long w3 = brow[bin * 4 + 3];
      f32x4 p[16];
      float mv[4] = {-3e38f, -3e38f, -3e38f, -3e38f};   // 4 independent chains
#pragma unroll
      for (int nt = 0; nt < 16; ++nt) {
        unsigned long long w = (nt < 4) ? w0 : (nt < 8) ? w1 : (nt < 12) ? w2 : w3;
#pragma unroll
        for (int r = 0; r < 4; ++r) {
          unsigned keep = (unsigned)(w >> (16 * (nt & 3) + 4 * fq + r)) & 1u;
          float sv = accs[nt][r];
          float v = keep ? sv : NEGV;
          p[nt][r] = v;
          mv[r] = fmaxf(mv[r], v);
        }
      }
      float m = fmaxf(fmaxf(mv[0], mv[1]), fmaxf(mv[2], mv[3]));
      m = fmaxf(m, __shfl_xor(m, 16));
      m = fmaxf(m, __shfl_xor(m, 32));
      f32x4 sacc = {0.f, 0.f, 0.f, 0.f};                // 4 independent chains
#pragma unroll
      for (int nt = 0; nt < 16; ++nt) {
#pragma unroll
        for (int r = 0; r < 4; ++r) p[nt][r] = __expf(p[nt][r] - m);
        sacc += p[nt];
      }
      float sum = (sacc[0] + sacc[1]) + (sacc[2] + sacc[3]);
      sum += __shfl_xor(sum, 16);
      sum += __shfl_xor(sum, 32);
      const float inv = 1.f / sum;
      float* prow = attn_out + ((size_t)((bin * 64 + b) * 8 + h)) * 65536 +
                    (size_t)q * 256;
#pragma unroll
      for (int nt = 0; nt < 16; ++nt) {
        float v0 = p[nt][0] * inv, v1 = p[nt][1] * inv;
        float v2 = p[nt][2] * inv, v3 = p[nt][3] * inv;
        f32x4 st = {v0, v1, v2, v3};
        __builtin_nontemporal_store(st, (f32x4*)(prow + nt * 16 + fq * 4));
        unsigned short u[4];
        u[0] = f2bf(v0); u[1] = f2bf(v1); u[2] = f2bf(v2); u[3] = f2bf(v3);
        int wb = (l15 << 9) | (nt << 5) | (fq << 3);
        *(uint2*)(plbase + (wb ^ swz)) = *(const uint2*)u;
      }
      asm volatile("s_waitcnt lgkmcnt(0)" ::: "memory");
      __builtin_amdgcn_sched_barrier(0);
      f32x4 acco[4] = {};
      __builtin_amdgcn_s_setprio(1);
#pragma unroll
      for (int c = 0; c < 8; ++c) {
        int rb = (l15 << 9) | (c << 6) | (fq << 4);
        bf16x8 pa = *(const bf16x8*)(plbase + (rb ^ swz));
#pragma unroll
        for (int nf = 0; nf < 4; ++nf) {
          bf16x8 bv = *(const bf16x8*)&Vt[nf * 16 + l15][c * 32 + fq * 8];
          acco[nf] = __builtin_amdgcn_mfma_f32_16x16x32_bf16(pa, bv, acco[nf], 0, 0, 0);
        }
      }
      __builtin_amdgcn_s_setprio(0);
#pragma unroll
      for (int nf = 0; nf < 4; ++nf)
#pragma unroll
        for (int r = 0; r < 4; ++r)
          mob[((size_t)(b * 256 + r0 + fq * 4 + r) * 3 + bin) * 512 +
              h * 64 + nf * 16 + l15] = f2bf(acco[nf][r]);
    }
  }
}

// ---------------------------------------------------------------------------
// Fused mlp2 + residual + LayerNorm (unchanged)
__global__ __launch_bounds__(256) void msa_mlp2ln(
    const unsigned short* __restrict__ h1b, const unsigned short* __restrict__ Ws2b,
    const float* __restrict__ bs2, const unsigned short* __restrict__ xb,
    const float* __restrict__ gamma, const float* __restrict__ beta,
    float* __restrict__ outp) {
  __shared__ __align__(16) unsigned short Al[32 * 32];
  __shared__ __align__(16) unsigned short Bl[512 * 32];
  __shared__ float red[2][2][32];
  const int tid = threadIdx.x;
  const int lane = tid & 63, wv = tid >> 6;
  const int wr = wv >> 1, wc = wv & 1;
  const int l15 = lane & 15, fq = lane >> 4;
  const int m0 = blockIdx.x * 32;
  f32x4 acc[16] = {};
  for (int kt = 0; kt < 512; kt += 32) {
    if (tid < 128) {
      int row = tid >> 2, c8 = (tid & 3) * 8;
      GLDS16(h1b + (size_t)(m0 + row) * 512 + kt + c8, &Al[tid * 8]);
    }
#pragma unroll
    for (int i = 0; i < 8; ++i) {
      int c = tid + i * 256;
      int row = c >> 2, c8 = (c & 3) * 8;
      GLDS16(Ws2b + (size_t)row * 512 + kt + c8, &Bl[c * 8]);
    }
    __syncthreads();
    bf16x8 af = *(const bf16x8*)&Al[(wr * 16 + l15) * 32 + fq * 8];
#pragma unroll
    for (int nt = 0; nt < 16; ++nt) {
      bf16x8 bfr = *(const bf16x8*)&Bl[(wc * 256 + nt * 16 + l15) * 32 + fq * 8];
      acc[nt] = __builtin_amdgcn_mfma_f32_16x16x32_bf16(af, bfr, acc[nt], 0, 0, 0);
    }
    __syncthreads();
  }
  float vals[16][4];
#pragma unroll
  for (int nt = 0; nt < 16; ++nt) {
    const int n = wc * 256 + nt * 16 + l15;
    const float bval = bs2[n];
#pragma unroll
    for (int r = 0; r < 4; ++r) {
      const int m = m0 + wr * 16 + fq * 4 + r;
      vals[nt][r] = acc[nt][r] + bval + bf2f(xb[(size_t)m * 512 + n]);
    }
  }
  const int ridx = wr * 16 + fq * 4;
#pragma unroll
  for (int r = 0; r < 4; ++r) {
    float s = 0.f;
#pragma unroll
    for (int nt = 0; nt < 16; ++nt) s += vals[nt][r];
    s += __shfl_xor(s, 1); s += __shfl_xor(s, 2);
    s += __shfl_xor(s, 4); s += __shfl_xor(s, 8);
    if (l15 == 0) red[0][wc][ridx + r] = s;
  }
  __syncthreads();
  float mu[4];
#pragma unroll
  for (int r = 0; r < 4; ++r)
    mu[r] = (red[0][0][ridx + r] + red[0][1][ridx + r]) * (1.f / 512.f);
#pragma unroll
  for (int r = 0; r < 4; ++r) {
    float s = 0.f;
#pragma unroll
    for (int nt = 0; nt < 16; ++nt) {
      float d = vals[nt][r] - mu[r];
      s += d * d;
    }
    s += __shfl_xor(s, 1); s += __shfl_xor(s, 2);
    s += __shfl_xor(s, 4); s += __shfl_xor(s, 8);
    if (l15 == 0) red[1][wc][ridx + r] = s;
  }
  __syncthreads();
  float iv[4];
#pragma unroll
  for (int r = 0; r < 4; ++r) {
    float var = (red[1][0][ridx + r] + red[1][1][ridx + r]) * (1.f / 512.f);
    iv[r] = 1.f / sqrtf(var + 1e-6f);
  }
#pragma unroll
  for (int nt = 0; nt < 16; ++nt) {
    const int n = wc * 256 + nt * 16 + l15;
    const float g = gamma[n], be = beta[n];
#pragma unroll
    for (int r = 0; r < 4; ++r) {
      const int m = m0 + wr * 16 + fq * 4 + r;
      outp[(size_t)m * 512 + n] = (vals[nt][r] - mu[r]) * iv[r] * g + be;
    }
  }
}

// ---------------------------------------------------------------------------
extern "C" void kernel_launch(void* const* d_in, const int* in_sizes, int n_in,
                              void* d_out, int out_size, void* d_ws, size_t ws_size,
                              hipStream_t stream) {
  (void)in_sizes; (void)n_in; (void)out_size; (void)ws_size;
  const float* x        = (const float*)d_in[0];
  const float* dist     = (const float*)d_in[1];
  const float* dist_bar = (const float*)d_in[2];
  const float* mask     = (const float*)d_in[3];
  const float* Wq  = (const float*)d_in[4];  const float* bq  = (const float*)d_in[5];
  const float* Wk  = (const float*)d_in[6];  const float* bk  = (const float*)d_in[7];
  const float* Wv  = (const float*)d_in[8];  const float* bv  = (const float*)d_in[9];
  const float* Wa  = (const float*)d_in[10]; const float* ba  = (const float*)d_in[11];
  const float* Ws1 = (const float*)d_in[12]; const float* bs1 = (const float*)d_in[13];
  const float* Ws2 = (const float*)d_in[14]; const float* bs2 = (const float*)d_in[15];
  const float* gamma = (const float*)d_in[16]; const float* beta = (const float*)d_in[17];

  char* w8 = (char*)d_ws;
  const size_t SZ = 8388608;                         // 16384*512
  unsigned short* qkvb = (unsigned short*)(w8 + 0);            // 50.3 MB [16384][1536]
  unsigned short* mob  = (unsigned short*)(w8 + 50331648);     // 50.3 MB [16384][1536]
  unsigned short* xb   = (unsigned short*)(w8 + 100663296);    // 16.8 MB
  unsigned short* Wqkvb= (unsigned short*)(w8 + 117440512);    // 1.6 MB [1536][512]
  unsigned short* Ws2b = (unsigned short*)(w8 + 119013376);    // 0.5 MB
  unsigned short* Wcatb= (unsigned short*)(w8 + 119537664);    // 1.6 MB [512][1536]
  float* bcomb = (float*)(w8 + 121110528);                     // 2 KB
  float* bqkv  = (float*)(w8 + 121112576);                     // 6 KB
  unsigned long long* bits = (unsigned long long*)(w8 + 121118720);  // 1.6 MB
  unsigned short* h1b = qkvb;                        // qkvb dead after msa_fused
  float* outp = (float*)d_out;
  float* attn = outp + SZ;                           // [3,B,8,256,256] fp32

  msa_prep<<<13825, 256, 0, stream>>>(x, Wq, Wk, Wv, Ws2, Ws1, Wa, bq, bk, bv,
                                      ba, bs1, dist, dist_bar, mask,
                                      xb, Wqkvb, Ws2b, Wcatb, bcomb, bqkv, bits);

  // qkv = x @ [Wq;Wk;Wv]^T + bqkv  (q columns pre-scaled by 0.125)
  msa_gemm_mfma<0, 0, 1, 32, 1, 128><<<dim3(128, 12), 256, 0, stream>>>(
      xb, 512, Wqkvb, 512, bqkv, nullptr, qkvb, 1536, 512);

  msa_fused<<<512, 512, 0, stream>>>(qkvb, bits, attn, mob);

  // h1b = silu(mob @ Wcatb^T + bcomb)
  msa_gemm_mfma<1, 0, 1, 32, 0, 64><<<dim3(256, 4), 256, 0, stream>>>(
      mob, 1536, Wcatb, 1536, bcomb, nullptr, h1b, 512, 1536);

  // out = LN(h1b @ Ws2b^T + bs2 + xb) * gamma + beta
  msa_mlp2ln<<<512, 256, 0, stream>>>(h1b, Ws2b, bs2, xb, gamma, beta, outp);
}